// Round 7
// baseline (405.338 us; speedup 1.0000x reference)
//
#include <hip/hip_runtime.h>
#include <stdint.h>

#define NN 20000
#define NE 200000
#define NG 128
#define NJOBS 12500  // 16-edge jobs
#define SLOTS 2048   // (1024/2 blocks per half) * 4 waves
#define FINBLKS 2500

typedef __attribute__((ext_vector_type(8))) short short8;
typedef __attribute__((ext_vector_type(4))) float f32x4;
typedef __attribute__((ext_vector_type(4))) int   int4v;
typedef __attribute__((ext_vector_type(2))) unsigned int uint2v;

static __device__ __forceinline__ float bf2f(short s) {
    union { unsigned int u; float f; } x;
    x.u = ((unsigned int)(unsigned short)s) << 16;
    return x.f;
}
static __device__ __forceinline__ unsigned short f2bf(float f) {
    unsigned int u = __builtin_bit_cast(unsigned int, f);
    u += 0x7fffu + ((u >> 16) & 1u);
    return (unsigned short)(u >> 16);
}
// pack two floats into a dword of two bf16 (a low, b high): 2 add + 1 v_perm
static __device__ __forceinline__ unsigned int pack2bf(float a, float b) {
    unsigned int u0 = __builtin_bit_cast(unsigned int, a) + 0x8000u;
    unsigned int u1 = __builtin_bit_cast(unsigned int, b) + 0x8000u;
    return __builtin_amdgcn_perm(u1, u0, 0x07060302u);
}
// per-wave inline dtype detect: all lanes read x[0..63]; bf16 low-short exp
// field lands in [100,140] w.p. ~0.99 vs ~0.16 for fp32 mantissa bits.
static __device__ __forceinline__ int detect_isbf(const unsigned int* x) {
    unsigned int u = x[threadIdx.x & 63];
    unsigned int el = (u >> 7) & 0xffu;
    unsigned long long bm = __ballot((el >= 100u) && (el <= 140u));
    return __popcll(bm) > 32;
}

// ------------------------------------------------------------------ kernel 1:
// block-role split (all roles independent; all must precede edge1):
//   blocks [0,2500):    node embed + layer-1 root init (h0, aggA)
//   blocks [2500,4327): W2T transpose, w1t/b1f, pooled zero, finctr zero,
//                       ea -> bf16 workspace
//   blocks [4327,4952): zero aggB (for edge2's atomic-init of the root term)
__global__ __launch_bounds__(256) void k_prep_all(
    const void* x, const void* nfcw, const void* nfcb,
    const void* root1, const void* bias1,
    const void* w2a, const void* b2a, const void* w2b, const void* b2b,
    const void* w1a, const void* b1a, const void* w1b, const void* b1b,
    const void* ea,
    float* __restrict__ h0, float* __restrict__ aggA, float* __restrict__ aggB,
    short* __restrict__ W2Ta, short* __restrict__ W2Tb,
    short* __restrict__ w1t_ws, float* __restrict__ b1f_ws,
    float* __restrict__ pooled, short* __restrict__ ea_ws,
    int* __restrict__ finctr) {
    const int isbf = detect_isbf((const unsigned int*)x);
    const int b = blockIdx.x;

    if (b < 2500) {  // ---- role A: embed + aggA init ----
        __shared__ float wf[64 * 32];
        __shared__ float rf[32 * 32];
        __shared__ float bfs[32];
        __shared__ float rb[32];
        __shared__ float hrow[8][33];
        for (int i = threadIdx.x; i < 64 * 32; i += 256)
            wf[i] = isbf ? bf2f(((const short*)nfcw)[i]) : ((const float*)nfcw)[i];
        for (int i = threadIdx.x; i < 32 * 32; i += 256)
            rf[i] = isbf ? bf2f(((const short*)root1)[i]) : ((const float*)root1)[i];
        if (threadIdx.x < 32) {
            bfs[threadIdx.x] = isbf ? bf2f(((const short*)nfcb)[threadIdx.x])
                                    : ((const float*)nfcb)[threadIdx.x];
            rb[threadIdx.x]  = isbf ? bf2f(((const short*)bias1)[threadIdx.x])
                                    : ((const float*)bias1)[threadIdx.x];
        }
        __syncthreads();
        int t = b * 256 + threadIdx.x;
        int v = t >> 5, c = t & 31, vl = threadIdx.x >> 5;
        float acc = bfs[c];
        if (isbf) {
            const short* xr = (const short*)x + (size_t)v * 64;
#pragma unroll
            for (int q = 0; q < 64; ++q) acc += bf2f(xr[q]) * wf[q * 32 + c];
        } else {
            const float* xr = (const float*)x + (size_t)v * 64;
#pragma unroll
            for (int q = 0; q < 64; ++q) acc += xr[q] * wf[q * 32 + c];
        }
        float hv = acc > 0.f ? acc : 0.01f * acc;
        h0[t] = hv;
        hrow[vl][c] = hv;
        __syncthreads();
        float a2 = rb[c];
#pragma unroll
        for (int q = 0; q < 32; ++q) a2 += hrow[vl][q] * rf[q * 32 + c];
        aggA[t] = a2;
        return;
    }
    if (b < 4327) {  // ---- role B: weight prep ----
        const int bb = b - 2500;
        if (bb == 0) {
            for (int i = threadIdx.x; i < NG * 32; i += 256) pooled[i] = 0.f;
            if (threadIdx.x == 0) *finctr = 0;
        }
        if (bb == 1) {
            for (int i = threadIdx.x; i < 1024; i += 256) {
                int layer = i >> 9, jj = i & 511, c = jj >> 4, q = jj & 15;
                const void* w1p = layer ? w1b : w1a;
                w1t_ws[i] = isbf ? ((const short*)w1p)[q * 32 + c]
                                 : (short)f2bf(((const float*)w1p)[q * 32 + c]);
            }
            for (int i = threadIdx.x; i < 64; i += 256) {
                int layer = i >> 5, c = i & 31;
                const void* b1p = layer ? b1b : b1a;
                b1f_ws[i] = isbf ? bf2f(((const short*)b1p)[c])
                                 : ((const float*)b1p)[c];
            }
        }
        int t = bb * 256 + threadIdx.x;
        if (t < 2 * 32 * 1056) {
            int layer = t / (32 * 1056);
            int r = t - layer * (32 * 1056);
            int o = r / 1056, kp = r - o * 1056;
            const void* w2 = layer ? w2b : w2a;
            const void* b2 = layer ? b2b : b2a;
            int idx; const void* sp;
            if (kp < 1024) { int kk = kp >> 5, i = kp & 31; idx = kk * 1024 + i * 32 + o; sp = w2; }
            else           { int i = kp - 1024;             idx = i * 32 + o;             sp = b2; }
            short v = isbf ? ((const short*)sp)[idx] : (short)f2bf(((const float*)sp)[idx]);
            (layer ? W2Tb : W2Ta)[o * 1056 + kp] = v;
            return;
        }
        int u = t - 2 * 32 * 1056;
        if (u < NE * 2 && !isbf) {  // 400000 threads x 8 elems
            const float* p = (const float*)ea + (size_t)u * 8;
            f32x4 f0 = *(const f32x4*)p;
            f32x4 f1 = *(const f32x4*)(p + 4);
            union { unsigned int d[4]; short8 v; } o8;
            o8.d[0] = pack2bf(f0[0], f0[1]);
            o8.d[1] = pack2bf(f0[2], f0[3]);
            o8.d[2] = pack2bf(f1[0], f1[1]);
            o8.d[3] = pack2bf(f1[2], f1[3]);
            *(short8*)&ea_ws[(size_t)u * 8] = o8.v;
        }
        return;
    }
    {  // ---- role C: zero aggB ----
        int idx = (b - 4327) * 256 + threadIdx.x;
        if (idx < NN * 32 / 4) {
            f32x4 z = {0.f, 0.f, 0.f, 0.f};
            ((f32x4*)aggB)[idx] = z;
        }
    }
}

// ------------------------------------------------------------------ edge kernel:
// 16-edge jobs (NJOBS=12500, 6.1 jobs/slot -> makespan inflation 1.147, was
// 1.31 at 32-edge).  K split in halves across block pairs; h1 bf16 in LDS;
// LDS 37.5KB -> 4 blocks/CU.  msg = P @ W2' factored per K-step s(=kk):
// U_s = mfma(bf16(hsrc), B_s, 0); acc += h1[:,kk] (*) U_s.  Deep pipeline:
// next job's gather issued right after the hsbf convert; dst prefetched one
// job ahead so no wait couples to atomic completion.
// layer2==1 additionally: (a) block prologue computes 625 elems of the root2
// init  aggB += lrelu(aggA)@root2 + bias2  via atomicAdd (aggB pre-zeroed) --
// replaces the k_mid launch; (b) lrelu applied to gathered aggA rows inline.
__global__ __launch_bounds__(256, 4) void k_edge(
    const float* __restrict__ h_in,   // [N,32] fp32 (h0 or aggA)
    const short* __restrict__ W2T,    // [32][1056] bf16
    const short* __restrict__ w1pre,  // [32 c][16 q] bf16 transposed (this layer)
    const float* __restrict__ b1pre,  // [32] fp32 (this layer)
    const int* __restrict__ src, const int* __restrict__ dst,
    const short* __restrict__ ea_bf,  // [E][16] bf16 (pre-converted or orig)
    const short* __restrict__ ea_ws,
    const unsigned int* xdet,
    float* agg,
    const int layer2, const void* rootp, const void* biasp) {
    __shared__ __align__(16) short w2t[32 * 546];    // 34.9KB, row 273 dw (odd)
    __shared__ __align__(16) short h1l[4 * 16 * 20]; // 2.56KB, per-wave [kk16][edge16+pad]

    const int isbf = detect_isbf(xdet);
    const short* eap = isbf ? ea_bf : ea_ws;

    const int half = blockIdx.x & 1;
    const int k0   = half ? 512 : 0;
    const int S17  = half;               // 1 -> extra bias step
    const int KS   = 546;                // LDS row stride (shorts), 273 dw (odd)
    const int KLEN = half ? 544 : 512;

    { // stage W2T[o][k0..k0+KLEN) -> LDS
        int cpr = KLEN >> 3;
        int chunks = 32 * cpr;
        for (int idx = threadIdx.x; idx < chunks; idx += 256) {
            int o = idx / cpr, t8 = idx - o * cpr;
            *(short8*)&w2t[o * KS + (t8 << 3)] =
                *(const short8*)&W2T[o * 1056 + k0 + (t8 << 3)];
        }
    }

    if (layer2) {  // ---- fused k_mid: this block's 625-elem slice of aggB init ----
        const int base = blockIdx.x * 625;
        for (int i = threadIdx.x; i < 625; i += 256) {
            int t = base + i;
            int v = t >> 5, c = t & 31;
            const float* ar = h_in + (size_t)v * 32;
            float acc = isbf ? bf2f(((const short*)biasp)[c]) : ((const float*)biasp)[c];
#pragma unroll
            for (int q = 0; q < 32; ++q) {
                float hv = ar[q];
                hv = hv > 0.f ? hv : 0.01f * hv;
                float wv = isbf ? bf2f(((const short*)rootp)[q * 32 + c])
                                : ((const float*)rootp)[q * 32 + c];
                acc += hv * wv;
            }
            atomicAdd(&agg[t], acc);
        }
    }
    __syncthreads();

    const int lane = threadIdx.x & 63;
    const int wid  = threadIdx.x >> 6;
    const int m    = lane & 15;
    const int quad = lane >> 4;
    const int wb   = wid * (16 * 20);

    // B-fragment of w1 (K padded 16->32 with zero rows -> quads 2,3 zero)
    short8 w1frag = {0, 0, 0, 0, 0, 0, 0, 0};
    if (quad < 2) {
        int c = m + (half << 4);
        w1frag = *(const short8*)&w1pre[c * 16 + ((quad & 1) << 3)];
    }
    const float b1v = b1pre[m + (half << 4)];
    const f32x4 zero4 = {0.f, 0.f, 0.f, 0.f};

    int j = (blockIdx.x >> 1) * 4 + wid;  // slot in [0,2048)

    // ---- prologue: land job j inputs, dst(j), src(j+SLOTS) ----
    short8 eafc;
    f32x4 hs[2];
    int srcn;
    int4v dvc;
    {
        const int e0 = j << 4;
        eafc = *(const short8*)&eap[(size_t)(e0 + m) * 16 + ((quad & 1) << 3)];
        int s0 = src[e0 + m];
        const float* hr = h_in + (size_t)s0 * 32 + (quad << 3);
        hs[0] = *(const f32x4*)hr;
        hs[1] = *(const f32x4*)(hr + 4);
        dvc = *(const int4v*)&dst[e0 + (quad << 2)];
        const int en = (j + SLOTS) < NJOBS ? ((j + SLOTS) << 4) : 0;
        srcn = src[en + m];
    }

    while (j < NJOBS) {
        const int jn = j + SLOTS;

        // ---- phase 1: h1 = relu(ea@w1+b1) -> bf16 [kk][edge] in LDS ----
        {
            f32x4 hacc = __builtin_amdgcn_mfma_f32_16x16x32_bf16(
                eafc, w1frag, zero4, 0, 0, 0);
            float v0 = fmaxf(hacc[0] + b1v, 0.f);
            float v1 = fmaxf(hacc[1] + b1v, 0.f);
            float v2 = fmaxf(hacc[2] + b1v, 0.f);
            float v3 = fmaxf(hacc[3] + b1v, 0.f);
            uint2v dl; dl[0] = pack2bf(v0, v1); dl[1] = pack2bf(v2, v3);
            // C/D: row(edge)=quad*4+r, col(kk)=m -> h1l[m][quad*4+r]
            *(uint2v*)&h1l[wb + m * 20 + (quad << 2)] = dl;
        }
        __asm volatile("s_waitcnt lgkmcnt(0)" ::: "memory");

        // prefetch next job's ea (streaming; consumed next phase 1)
        if (jn < NJOBS) {
            const int en = jn << 4;
            eafc = *(const short8*)&eap[(size_t)(en + m) * 16 + ((quad & 1) << 3)];
        }

        // ---- convert hsrc -> bf16 A-fragment ONCE per job (lrelu inline L2) ----
        short8 hsbf;
        {
            f32x4 g0 = hs[0], g1 = hs[1];
            if (layer2) {
#pragma unroll
                for (int p = 0; p < 4; ++p) {
                    g0[p] = g0[p] > 0.f ? g0[p] : 0.01f * g0[p];
                    g1[p] = g1[p] > 0.f ? g1[p] : 0.01f * g1[p];
                }
            }
            union { unsigned int du[4]; short8 v; } a;
            a.du[0] = pack2bf(g0[0], g0[1]);
            a.du[1] = pack2bf(g0[2], g0[3]);
            a.du[2] = pack2bf(g1[0], g1[1]);
            a.du[3] = pack2bf(g1[2], g1[3]);
            hsbf = a.v;
        }

        // ---- issue next job's gather/dst NOW (hs regs just freed) ----
        int4v dvn = dvc;
        if (jn < NJOBS) {
            const float* hr = h_in + (size_t)srcn * 32 + (quad << 3);
            hs[0] = *(const f32x4*)hr;
            hs[1] = *(const f32x4*)(hr + 4);
            dvn = *(const int4v*)&dst[(jn << 4) + (quad << 2)];
            const int jn2 = jn + SLOTS;
            if (jn2 < NJOBS) srcn = src[(jn2 << 4) + m];
        }

        // ---- phase 2: K loop; U_s = hsrc@B_s via MFMA, fp32 row-scale by h1 ----
        f32x4 acc0 = zero4, acc1 = zero4;
#pragma unroll
        for (int s = 0; s < 16; ++s) {
            short8 bf0 = *(const short8*)&w2t[m * KS + (s << 5) + (quad << 3)];
            short8 bf1 = *(const short8*)&w2t[(m + 16) * KS + (s << 5) + (quad << 3)];
            uint2v hd = *(const uint2v*)&h1l[wb + s * 20 + (quad << 2)];
            f32x4 hv;
            hv[0] = __builtin_bit_cast(float, hd[0] << 16);
            hv[1] = __builtin_bit_cast(float, hd[0] & 0xffff0000u);
            hv[2] = __builtin_bit_cast(float, hd[1] << 16);
            hv[3] = __builtin_bit_cast(float, hd[1] & 0xffff0000u);
            f32x4 u0 = __builtin_amdgcn_mfma_f32_16x16x32_bf16(hsbf, bf0, zero4, 0, 0, 0);
            f32x4 u1 = __builtin_amdgcn_mfma_f32_16x16x32_bf16(hsbf, bf1, zero4, 0, 0, 0);
            acc0 += hv * u0;
            acc1 += hv * u1;
        }
        if (S17) {  // bias row (coefficient 1.0): accumulate via MFMA directly
            const int s = 16;
            short8 bf0 = *(const short8*)&w2t[m * KS + (s << 5) + (quad << 3)];
            short8 bf1 = *(const short8*)&w2t[(m + 16) * KS + (s << 5) + (quad << 3)];
            acc0 = __builtin_amdgcn_mfma_f32_16x16x32_bf16(hsbf, bf0, acc0, 0, 0, 0);
            acc1 = __builtin_amdgcn_mfma_f32_16x16x32_bf16(hsbf, bf1, acc1, 0, 0, 0);
        }

        // ---- epilogue: atomic scatter (dvc loaded BEFORE prev atomics) ----
#pragma unroll
        for (int r = 0; r < 4; ++r) {
            float* ap = agg + (size_t)dvc[r] * 32 + m;
            atomicAdd(ap, acc0[r]);
            atomicAdd(ap + 16, acc1[r]);
        }
        dvc = dvn;
        j = jn;
    }
}

// ------------------------------------------------------------------ kernel 4:
// layer-2 node output + pooled (LDS pre-agg) + LAST-BLOCK graph head
// (threadfence + done-counter; pooled read back via atomicAdd(p,0) so the
// read happens at the coherence point -- XCD L2s are not cross-coherent).
__global__ __launch_bounds__(256) void k_final(
    const float* __restrict__ agg, const int* __restrict__ batch,
    const unsigned int* xdet, void* __restrict__ out, float* pooled,
    const void* fcw, const void* fcb, int* __restrict__ finctr) {
    const int isbf = detect_isbf(xdet);
    __shared__ float gacc[8][32];
    __shared__ int g0s;
    __shared__ int lastf;
    ((float*)gacc)[threadIdx.x] = 0.f;
    if (threadIdx.x == 0) g0s = batch[blockIdx.x * 8];
    __syncthreads();
    int t = blockIdx.x * 256 + threadIdx.x;
    float v = agg[t];
    v = v > 0.f ? v : 0.01f * v;
    if (isbf) ((short*)out)[4096 + t] = (short)f2bf(v);
    else      ((float*)out)[4096 + t] = v;
    int g = batch[t >> 5];
    int rel = g - g0s;
    int c = t & 31;
    if (rel < 8) atomicAdd(&gacc[rel][c], v);
    else         atomicAdd(&pooled[g * 32 + c], v);
    __syncthreads();
    {
        int gi = threadIdx.x >> 5, cc = threadIdx.x & 31;
        float s = gacc[gi][cc];
        if (s != 0.f) atomicAdd(&pooled[(g0s + gi) * 32 + cc], s);
    }
    __threadfence();
    __syncthreads();
    if (threadIdx.x == 0) lastf = (atomicAdd(finctr, 1) == FINBLKS - 1);
    __syncthreads();
    if (!lastf) return;

    // ---- graph head (runs once, in the last-arriving block) ----
    int lane32 = threadIdx.x & 31;
    int grp = threadIdx.x >> 5;  // 0..7
    for (int gb = 0; gb < NG; gb += 8) {
        int gg = gb + grp;
        float p = atomicAdd(&pooled[gg * 32 + lane32], 0.0f);  // coherent read
        float sq = p * p;
#pragma unroll
        for (int o = 16; o > 0; o >>= 1) sq += __shfl_xor(sq, o, 32);
        float inv = 1.0f / fmaxf(sqrtf(sq), 1e-12f);
        float pn = p * inv;
        float acc = isbf ? bf2f(((const short*)fcb)[lane32]) : ((const float*)fcb)[lane32];
#pragma unroll
        for (int q = 0; q < 32; ++q) {
            float pq = __shfl(pn, q, 32);
            float wv = isbf ? bf2f(((const short*)fcw)[q * 32 + lane32])
                            : ((const float*)fcw)[q * 32 + lane32];
            acc += pq * wv;
        }
        if (isbf) ((short*)out)[gg * 32 + lane32] = (short)f2bf(acc);
        else      ((float*)out)[gg * 32 + lane32] = acc;
    }
}

extern "C" void kernel_launch(void* const* d_in, const int* in_sizes, int n_in,
                              void* d_out, int out_size, void* d_ws, size_t ws_size,
                              hipStream_t stream) {
    (void)in_sizes; (void)n_in; (void)out_size; (void)ws_size;
    const void* x     = d_in[0];
    const int*  eidx  = (const int*)d_in[1];
    const void* ea    = d_in[2];
    const int*  batch = (const int*)d_in[3];
    const void* nfcw  = d_in[5];
    const void* nfcb  = d_in[6];
    const void* e1w1  = d_in[7];
    const void* e1b1  = d_in[8];
    const void* e1w2  = d_in[9];
    const void* e1b2  = d_in[10];
    const void* root1 = d_in[11];
    const void* bias1 = d_in[12];
    const void* e2w1  = d_in[13];
    const void* e2b1  = d_in[14];
    const void* e2w2  = d_in[15];
    const void* e2b2  = d_in[16];
    const void* root2 = d_in[17];
    const void* bias2 = d_in[18];
    const void* fcw   = d_in[19];
    const void* fcb   = d_in[20];
    const unsigned int* xdet = (const unsigned int*)x;

    char* ws = (char*)d_ws;
    float* h0     = (float*)ws; ws += (size_t)NN * 32 * 4;
    float* aggA   = (float*)ws; ws += (size_t)NN * 32 * 4;
    float* aggB   = (float*)ws; ws += (size_t)NN * 32 * 4;
    short* W2T1   = (short*)ws; ws += 32 * 1056 * 2;
    short* W2T2   = (short*)ws; ws += 32 * 1056 * 2;
    short* w1t_ws = (short*)ws; ws += 1024 * 2;
    float* b1f_ws = (float*)ws; ws += 64 * 4;
    float* pooled = (float*)ws; ws += NG * 32 * 4;
    short* ea_ws  = (short*)ws; ws += (size_t)NE * 16 * 2;
    int*   finctr = (int*)ws;   ws += sizeof(int);

    const int* srcp = eidx;
    const int* dstp = eidx + NE;

    // kernel 1: embed(2500) + prep(1827) + aggB-zero(625) = 4952 blocks
    k_prep_all<<<4952, 256, 0, stream>>>(
        x, nfcw, nfcb, root1, bias1,
        e1w2, e1b2, e2w2, e2b2, e1w1, e1b1, e2w1, e2b1, ea,
        h0, aggA, aggB, W2T1, W2T2, w1t_ws, b1f_ws, pooled, ea_ws, finctr);

    // layer 1
    k_edge<<<1024, 256, 0, stream>>>(h0, W2T1, w1t_ws, b1f_ws, srcp, dstp,
                                     (const short*)ea, ea_ws, xdet, aggA,
                                     0, nullptr, nullptr);
    // layer 2 (fused root2-init + inline lrelu on gathered aggA)
    k_edge<<<1024, 256, 0, stream>>>(aggA, W2T2, w1t_ws + 512, b1f_ws + 32, srcp, dstp,
                                     (const short*)ea, ea_ws, xdet, aggB,
                                     1, root2, bias2);
    // node output + pooled + last-block graph head
    k_final<<<FINBLKS, 256, 0, stream>>>(aggB, batch, xdet, d_out, pooled,
                                         fcw, fcb, finctr);
}

// Round 8
// 233.221 us; speedup vs baseline: 1.7380x; 1.7380x over previous
//
#include <hip/hip_runtime.h>
#include <stdint.h>

#define NN 20000
#define NE 200000
#define NG 128
#define NJOBS 12500  // 16-edge jobs
#define SLOTS 2048   // (1024/2 blocks per half) * 4 waves

typedef __attribute__((ext_vector_type(8))) short short8;
typedef __attribute__((ext_vector_type(4))) float f32x4;
typedef __attribute__((ext_vector_type(4))) int   int4v;
typedef __attribute__((ext_vector_type(2))) unsigned int uint2v;

static __device__ __forceinline__ float bf2f(short s) {
    union { unsigned int u; float f; } x;
    x.u = ((unsigned int)(unsigned short)s) << 16;
    return x.f;
}
static __device__ __forceinline__ unsigned short f2bf(float f) {
    unsigned int u = __builtin_bit_cast(unsigned int, f);
    u += 0x7fffu + ((u >> 16) & 1u);
    return (unsigned short)(u >> 16);
}
// pack two floats into a dword of two bf16 (a low, b high): 2 add + 1 v_perm
static __device__ __forceinline__ unsigned int pack2bf(float a, float b) {
    unsigned int u0 = __builtin_bit_cast(unsigned int, a) + 0x8000u;
    unsigned int u1 = __builtin_bit_cast(unsigned int, b) + 0x8000u;
    return __builtin_amdgcn_perm(u1, u0, 0x07060302u);
}
// per-wave inline dtype detect: all lanes read x[0..63]; bf16 low-short exp
// field lands in [100,140] w.p. ~0.99 vs ~0.16 for fp32 mantissa bits.
static __device__ __forceinline__ int detect_isbf(const unsigned int* x) {
    unsigned int u = x[threadIdx.x & 63];
    unsigned int el = (u >> 7) & 0xffu;
    unsigned long long bm = __ballot((el >= 100u) && (el <= 140u));
    return __popcll(bm) > 32;
}

// ------------------------------------------------------------------ kernel 1:
// block-role split (all roles independent; all must precede edge1):
//   blocks [0,2500):    node embed + layer-1 root init (h0, aggA)
//   blocks [2500,4327): W2T transpose, w1t/b1f, pooled zero,
//                       ea -> bf16 workspace
//   blocks [4327,4952): zero aggB (for edge2's atomic-init of the root term)
__global__ __launch_bounds__(256) void k_prep_all(
    const void* x, const void* nfcw, const void* nfcb,
    const void* root1, const void* bias1,
    const void* w2a, const void* b2a, const void* w2b, const void* b2b,
    const void* w1a, const void* b1a, const void* w1b, const void* b1b,
    const void* ea,
    float* __restrict__ h0, float* __restrict__ aggA, float* __restrict__ aggB,
    short* __restrict__ W2Ta, short* __restrict__ W2Tb,
    short* __restrict__ w1t_ws, float* __restrict__ b1f_ws,
    float* __restrict__ pooled, short* __restrict__ ea_ws) {
    const int isbf = detect_isbf((const unsigned int*)x);
    const int b = blockIdx.x;

    if (b < 2500) {  // ---- role A: embed + aggA init ----
        __shared__ float wf[64 * 32];
        __shared__ float rf[32 * 32];
        __shared__ float bfs[32];
        __shared__ float rb[32];
        __shared__ float hrow[8][33];
        for (int i = threadIdx.x; i < 64 * 32; i += 256)
            wf[i] = isbf ? bf2f(((const short*)nfcw)[i]) : ((const float*)nfcw)[i];
        for (int i = threadIdx.x; i < 32 * 32; i += 256)
            rf[i] = isbf ? bf2f(((const short*)root1)[i]) : ((const float*)root1)[i];
        if (threadIdx.x < 32) {
            bfs[threadIdx.x] = isbf ? bf2f(((const short*)nfcb)[threadIdx.x])
                                    : ((const float*)nfcb)[threadIdx.x];
            rb[threadIdx.x]  = isbf ? bf2f(((const short*)bias1)[threadIdx.x])
                                    : ((const float*)bias1)[threadIdx.x];
        }
        __syncthreads();
        int t = b * 256 + threadIdx.x;
        int v = t >> 5, c = t & 31, vl = threadIdx.x >> 5;
        float acc = bfs[c];
        if (isbf) {
            const short* xr = (const short*)x + (size_t)v * 64;
#pragma unroll
            for (int q = 0; q < 64; ++q) acc += bf2f(xr[q]) * wf[q * 32 + c];
        } else {
            const float* xr = (const float*)x + (size_t)v * 64;
#pragma unroll
            for (int q = 0; q < 64; ++q) acc += xr[q] * wf[q * 32 + c];
        }
        float hv = acc > 0.f ? acc : 0.01f * acc;
        h0[t] = hv;
        hrow[vl][c] = hv;
        __syncthreads();
        float a2 = rb[c];
#pragma unroll
        for (int q = 0; q < 32; ++q) a2 += hrow[vl][q] * rf[q * 32 + c];
        aggA[t] = a2;
        return;
    }
    if (b < 4327) {  // ---- role B: weight prep ----
        const int bb = b - 2500;
        if (bb == 0) {
            for (int i = threadIdx.x; i < NG * 32; i += 256) pooled[i] = 0.f;
        }
        if (bb == 1) {
            for (int i = threadIdx.x; i < 1024; i += 256) {
                int layer = i >> 9, jj = i & 511, c = jj >> 4, q = jj & 15;
                const void* w1p = layer ? w1b : w1a;
                w1t_ws[i] = isbf ? ((const short*)w1p)[q * 32 + c]
                                 : (short)f2bf(((const float*)w1p)[q * 32 + c]);
            }
            for (int i = threadIdx.x; i < 64; i += 256) {
                int layer = i >> 5, c = i & 31;
                const void* b1p = layer ? b1b : b1a;
                b1f_ws[i] = isbf ? bf2f(((const short*)b1p)[c])
                                 : ((const float*)b1p)[c];
            }
        }
        int t = bb * 256 + threadIdx.x;
        if (t < 2 * 32 * 1056) {
            int layer = t / (32 * 1056);
            int r = t - layer * (32 * 1056);
            int o = r / 1056, kp = r - o * 1056;
            const void* w2 = layer ? w2b : w2a;
            const void* b2 = layer ? b2b : b2a;
            int idx; const void* sp;
            if (kp < 1024) { int kk = kp >> 5, i = kp & 31; idx = kk * 1024 + i * 32 + o; sp = w2; }
            else           { int i = kp - 1024;             idx = i * 32 + o;             sp = b2; }
            short v = isbf ? ((const short*)sp)[idx] : (short)f2bf(((const float*)sp)[idx]);
            (layer ? W2Tb : W2Ta)[o * 1056 + kp] = v;
            return;
        }
        int u = t - 2 * 32 * 1056;
        if (u < NE * 2 && !isbf) {  // 400000 threads x 8 elems
            const float* p = (const float*)ea + (size_t)u * 8;
            f32x4 f0 = *(const f32x4*)p;
            f32x4 f1 = *(const f32x4*)(p + 4);
            union { unsigned int d[4]; short8 v; } o8;
            o8.d[0] = pack2bf(f0[0], f0[1]);
            o8.d[1] = pack2bf(f0[2], f0[3]);
            o8.d[2] = pack2bf(f1[0], f1[1]);
            o8.d[3] = pack2bf(f1[2], f1[3]);
            *(short8*)&ea_ws[(size_t)u * 8] = o8.v;
        }
        return;
    }
    {  // ---- role C: zero aggB ----
        int idx = (b - 4327) * 256 + threadIdx.x;
        if (idx < NN * 32 / 4) {
            f32x4 z = {0.f, 0.f, 0.f, 0.f};
            ((f32x4*)aggB)[idx] = z;
        }
    }
}

// ------------------------------------------------------------------ edge kernel:
// 16-edge jobs (NJOBS=12500, 6.1 jobs/slot -> makespan inflation 1.147).
// K split in halves across block pairs; h1 bf16 in LDS; LDS 37.5KB -> 4
// blocks/CU.  msg = P @ W2' factored per K-step s(=kk):
// U_s = mfma(bf16(hsrc), B_s, 0); acc += h1[:,kk] (*) U_s.  Deep pipeline:
// next job's gather issued right after the hsbf convert; dst prefetched one
// job ahead so no wait couples to atomic completion.
// layer2==1 additionally: (a) block prologue computes 625 elems of the root2
// init  aggB += lrelu(aggA)@root2 + bias2  via atomicAdd (aggB pre-zeroed) --
// replaces the k_mid launch; (b) lrelu applied to gathered aggA rows inline.
__global__ __launch_bounds__(256, 4) void k_edge(
    const float* __restrict__ h_in,   // [N,32] fp32 (h0 or aggA)
    const short* __restrict__ W2T,    // [32][1056] bf16
    const short* __restrict__ w1pre,  // [32 c][16 q] bf16 transposed (this layer)
    const float* __restrict__ b1pre,  // [32] fp32 (this layer)
    const int* __restrict__ src, const int* __restrict__ dst,
    const short* __restrict__ ea_bf,  // [E][16] bf16 (pre-converted or orig)
    const short* __restrict__ ea_ws,
    const unsigned int* xdet,
    float* agg,
    const int layer2, const void* rootp, const void* biasp) {
    __shared__ __align__(16) short w2t[32 * 546];    // 34.9KB, row 273 dw (odd)
    __shared__ __align__(16) short h1l[4 * 16 * 20]; // 2.56KB, per-wave [kk16][edge16+pad]

    const int isbf = detect_isbf(xdet);
    const short* eap = isbf ? ea_bf : ea_ws;

    const int half = blockIdx.x & 1;
    const int k0   = half ? 512 : 0;
    const int S17  = half;               // 1 -> extra bias step
    const int KS   = 546;                // LDS row stride (shorts), 273 dw (odd)
    const int KLEN = half ? 544 : 512;

    { // stage W2T[o][k0..k0+KLEN) -> LDS
        int cpr = KLEN >> 3;
        int chunks = 32 * cpr;
        for (int idx = threadIdx.x; idx < chunks; idx += 256) {
            int o = idx / cpr, t8 = idx - o * cpr;
            *(short8*)&w2t[o * KS + (t8 << 3)] =
                *(const short8*)&W2T[o * 1056 + k0 + (t8 << 3)];
        }
    }

    if (layer2) {  // ---- fused k_mid: this block's 625-elem slice of aggB init ----
        const int base = blockIdx.x * 625;
        for (int i = threadIdx.x; i < 625; i += 256) {
            int t = base + i;
            int v = t >> 5, c = t & 31;
            const float* ar = h_in + (size_t)v * 32;
            float acc = isbf ? bf2f(((const short*)biasp)[c]) : ((const float*)biasp)[c];
#pragma unroll
            for (int q = 0; q < 32; ++q) {
                float hv = ar[q];
                hv = hv > 0.f ? hv : 0.01f * hv;
                float wv = isbf ? bf2f(((const short*)rootp)[q * 32 + c])
                                : ((const float*)rootp)[q * 32 + c];
                acc += hv * wv;
            }
            atomicAdd(&agg[t], acc);
        }
    }
    __syncthreads();

    const int lane = threadIdx.x & 63;
    const int wid  = threadIdx.x >> 6;
    const int m    = lane & 15;
    const int quad = lane >> 4;
    const int wb   = wid * (16 * 20);

    // B-fragment of w1 (K padded 16->32 with zero rows -> quads 2,3 zero)
    short8 w1frag = {0, 0, 0, 0, 0, 0, 0, 0};
    if (quad < 2) {
        int c = m + (half << 4);
        w1frag = *(const short8*)&w1pre[c * 16 + ((quad & 1) << 3)];
    }
    const float b1v = b1pre[m + (half << 4)];
    const f32x4 zero4 = {0.f, 0.f, 0.f, 0.f};

    int j = (blockIdx.x >> 1) * 4 + wid;  // slot in [0,2048)

    // ---- prologue: land job j inputs, dst(j), src(j+SLOTS) ----
    short8 eafc;
    f32x4 hs[2];
    int srcn;
    int4v dvc;
    {
        const int e0 = j << 4;
        eafc = *(const short8*)&eap[(size_t)(e0 + m) * 16 + ((quad & 1) << 3)];
        int s0 = src[e0 + m];
        const float* hr = h_in + (size_t)s0 * 32 + (quad << 3);
        hs[0] = *(const f32x4*)hr;
        hs[1] = *(const f32x4*)(hr + 4);
        dvc = *(const int4v*)&dst[e0 + (quad << 2)];
        const int en = (j + SLOTS) < NJOBS ? ((j + SLOTS) << 4) : 0;
        srcn = src[en + m];
    }

    while (j < NJOBS) {
        const int jn = j + SLOTS;

        // ---- phase 1: h1 = relu(ea@w1+b1) -> bf16 [kk][edge] in LDS ----
        {
            f32x4 hacc = __builtin_amdgcn_mfma_f32_16x16x32_bf16(
                eafc, w1frag, zero4, 0, 0, 0);
            float v0 = fmaxf(hacc[0] + b1v, 0.f);
            float v1 = fmaxf(hacc[1] + b1v, 0.f);
            float v2 = fmaxf(hacc[2] + b1v, 0.f);
            float v3 = fmaxf(hacc[3] + b1v, 0.f);
            uint2v dl; dl[0] = pack2bf(v0, v1); dl[1] = pack2bf(v2, v3);
            // C/D: row(edge)=quad*4+r, col(kk)=m -> h1l[m][quad*4+r]
            *(uint2v*)&h1l[wb + m * 20 + (quad << 2)] = dl;
        }
        __asm volatile("s_waitcnt lgkmcnt(0)" ::: "memory");

        // prefetch next job's ea (streaming; consumed next phase 1)
        if (jn < NJOBS) {
            const int en = jn << 4;
            eafc = *(const short8*)&eap[(size_t)(en + m) * 16 + ((quad & 1) << 3)];
        }

        // ---- convert hsrc -> bf16 A-fragment ONCE per job (lrelu inline L2) ----
        short8 hsbf;
        {
            f32x4 g0 = hs[0], g1 = hs[1];
            if (layer2) {
#pragma unroll
                for (int p = 0; p < 4; ++p) {
                    g0[p] = g0[p] > 0.f ? g0[p] : 0.01f * g0[p];
                    g1[p] = g1[p] > 0.f ? g1[p] : 0.01f * g1[p];
                }
            }
            union { unsigned int du[4]; short8 v; } a;
            a.du[0] = pack2bf(g0[0], g0[1]);
            a.du[1] = pack2bf(g0[2], g0[3]);
            a.du[2] = pack2bf(g1[0], g1[1]);
            a.du[3] = pack2bf(g1[2], g1[3]);
            hsbf = a.v;
        }

        // ---- issue next job's gather/dst NOW (hs regs just freed) ----
        int4v dvn = dvc;
        if (jn < NJOBS) {
            const float* hr = h_in + (size_t)srcn * 32 + (quad << 3);
            hs[0] = *(const f32x4*)hr;
            hs[1] = *(const f32x4*)(hr + 4);
            dvn = *(const int4v*)&dst[(jn << 4) + (quad << 2)];
            const int jn2 = jn + SLOTS;
            if (jn2 < NJOBS) srcn = src[(jn2 << 4) + m];
        }

        // ---- phase 2: K loop; U_s = hsrc@B_s via MFMA, fp32 row-scale by h1 ----
        f32x4 acc0 = zero4, acc1 = zero4;
#pragma unroll
        for (int s = 0; s < 16; ++s) {
            short8 bf0 = *(const short8*)&w2t[m * KS + (s << 5) + (quad << 3)];
            short8 bf1 = *(const short8*)&w2t[(m + 16) * KS + (s << 5) + (quad << 3)];
            uint2v hd = *(const uint2v*)&h1l[wb + s * 20 + (quad << 2)];
            f32x4 hv;
            hv[0] = __builtin_bit_cast(float, hd[0] << 16);
            hv[1] = __builtin_bit_cast(float, hd[0] & 0xffff0000u);
            hv[2] = __builtin_bit_cast(float, hd[1] << 16);
            hv[3] = __builtin_bit_cast(float, hd[1] & 0xffff0000u);
            f32x4 u0 = __builtin_amdgcn_mfma_f32_16x16x32_bf16(hsbf, bf0, zero4, 0, 0, 0);
            f32x4 u1 = __builtin_amdgcn_mfma_f32_16x16x32_bf16(hsbf, bf1, zero4, 0, 0, 0);
            acc0 += hv * u0;
            acc1 += hv * u1;
        }
        if (S17) {  // bias row (coefficient 1.0): accumulate via MFMA directly
            const int s = 16;
            short8 bf0 = *(const short8*)&w2t[m * KS + (s << 5) + (quad << 3)];
            short8 bf1 = *(const short8*)&w2t[(m + 16) * KS + (s << 5) + (quad << 3)];
            acc0 = __builtin_amdgcn_mfma_f32_16x16x32_bf16(hsbf, bf0, acc0, 0, 0, 0);
            acc1 = __builtin_amdgcn_mfma_f32_16x16x32_bf16(hsbf, bf1, acc1, 0, 0, 0);
        }

        // ---- epilogue: atomic scatter (dvc loaded BEFORE prev atomics) ----
#pragma unroll
        for (int r = 0; r < 4; ++r) {
            float* ap = agg + (size_t)dvc[r] * 32 + m;
            atomicAdd(ap, acc0[r]);
            atomicAdd(ap + 16, acc1[r]);
        }
        dvc = dvn;
        j = jn;
    }
}

// ------------------------------------------------------------------ layer2 out
// LDS pre-aggregation of pooled: batch is sorted, so an 8-node block spans
// ~1-2 graphs -> global atomics drop 640k -> ~10k.  (No fence / no grid-sync:
// round-7's threadfence+done-counter pattern cost 191us of pure stall.)
__global__ __launch_bounds__(256) void k_final_nodes(
    const float* __restrict__ agg, const int* __restrict__ batch,
    const unsigned int* xdet, void* __restrict__ out, float* pooled) {
    const int isbf = detect_isbf(xdet);
    __shared__ float gacc[8][32];
    __shared__ int g0s;
    ((float*)gacc)[threadIdx.x] = 0.f;
    if (threadIdx.x == 0) g0s = batch[blockIdx.x * 8];
    __syncthreads();
    int t = blockIdx.x * 256 + threadIdx.x;
    float v = agg[t];
    v = v > 0.f ? v : 0.01f * v;
    if (isbf) ((short*)out)[4096 + t] = (short)f2bf(v);
    else      ((float*)out)[4096 + t] = v;
    int g = batch[t >> 5];
    int rel = g - g0s;
    int c = t & 31;
    if (rel < 8) atomicAdd(&gacc[rel][c], v);
    else         atomicAdd(&pooled[g * 32 + c], v);
    __syncthreads();
    {
        int gi = threadIdx.x >> 5, cc = threadIdx.x & 31;
        float s = gacc[gi][cc];
        if (s != 0.f) atomicAdd(&pooled[(g0s + gi) * 32 + cc], s);
    }
}

// ------------------------------------------------------------------ graph head
__global__ __launch_bounds__(64) void k_graph_out(
    const float* __restrict__ pooled, const void* fcw, const void* fcb,
    const unsigned int* xdet, void* __restrict__ out) {
    const int isbf = detect_isbf(xdet);
    int g = blockIdx.x;
    int t = threadIdx.x;
    __shared__ float pn[32];
    if (t < 32) {
        float p = pooled[g * 32 + t];
        float sq = p * p;
#pragma unroll
        for (int o = 16; o > 0; o >>= 1) sq += __shfl_xor(sq, o, 64);
        float inv = 1.0f / fmaxf(sqrtf(sq), 1e-12f);
        pn[t] = p * inv;
    }
    __syncthreads();
    if (t < 32) {
        float acc = isbf ? bf2f(((const short*)fcb)[t]) : ((const float*)fcb)[t];
#pragma unroll
        for (int q = 0; q < 32; ++q) {
            float wv = isbf ? bf2f(((const short*)fcw)[q * 32 + t])
                            : ((const float*)fcw)[q * 32 + t];
            acc += pn[q] * wv;
        }
        if (isbf) ((short*)out)[g * 32 + t] = (short)f2bf(acc);
        else      ((float*)out)[g * 32 + t] = acc;
    }
}

extern "C" void kernel_launch(void* const* d_in, const int* in_sizes, int n_in,
                              void* d_out, int out_size, void* d_ws, size_t ws_size,
                              hipStream_t stream) {
    (void)in_sizes; (void)n_in; (void)out_size; (void)ws_size;
    const void* x     = d_in[0];
    const int*  eidx  = (const int*)d_in[1];
    const void* ea    = d_in[2];
    const int*  batch = (const int*)d_in[3];
    const void* nfcw  = d_in[5];
    const void* nfcb  = d_in[6];
    const void* e1w1  = d_in[7];
    const void* e1b1  = d_in[8];
    const void* e1w2  = d_in[9];
    const void* e1b2  = d_in[10];
    const void* root1 = d_in[11];
    const void* bias1 = d_in[12];
    const void* e2w1  = d_in[13];
    const void* e2b1  = d_in[14];
    const void* e2w2  = d_in[15];
    const void* e2b2  = d_in[16];
    const void* root2 = d_in[17];
    const void* bias2 = d_in[18];
    const void* fcw   = d_in[19];
    const void* fcb   = d_in[20];
    const unsigned int* xdet = (const unsigned int*)x;

    char* ws = (char*)d_ws;
    float* h0     = (float*)ws; ws += (size_t)NN * 32 * 4;
    float* aggA   = (float*)ws; ws += (size_t)NN * 32 * 4;
    float* aggB   = (float*)ws; ws += (size_t)NN * 32 * 4;
    short* W2T1   = (short*)ws; ws += 32 * 1056 * 2;
    short* W2T2   = (short*)ws; ws += 32 * 1056 * 2;
    short* w1t_ws = (short*)ws; ws += 1024 * 2;
    float* b1f_ws = (float*)ws; ws += 64 * 4;
    float* pooled = (float*)ws; ws += NG * 32 * 4;
    short* ea_ws  = (short*)ws; ws += (size_t)NE * 16 * 2;

    const int* srcp = eidx;
    const int* dstp = eidx + NE;

    // kernel 1: embed(2500) + prep(1827) + aggB-zero(625) = 4952 blocks
    k_prep_all<<<4952, 256, 0, stream>>>(
        x, nfcw, nfcb, root1, bias1,
        e1w2, e1b2, e2w2, e2b2, e1w1, e1b1, e2w1, e2b1, ea,
        h0, aggA, aggB, W2T1, W2T2, w1t_ws, b1f_ws, pooled, ea_ws);

    // layer 1
    k_edge<<<1024, 256, 0, stream>>>(h0, W2T1, w1t_ws, b1f_ws, srcp, dstp,
                                     (const short*)ea, ea_ws, xdet, aggA,
                                     0, nullptr, nullptr);
    // layer 2 (fused root2-init + inline lrelu on gathered aggA)
    k_edge<<<1024, 256, 0, stream>>>(aggA, W2T2, w1t_ws + 512, b1f_ws + 32, srcp, dstp,
                                     (const short*)ea, ea_ws, xdet, aggB,
                                     1, root2, bias2);
    // node output + pooled
    k_final_nodes<<<(NN * 32 + 255) / 256, 256, 0, stream>>>(aggB, batch, xdet, d_out, pooled);
    // graph head
    k_graph_out<<<NG, 64, 0, stream>>>(pooled, fcw, fcb, xdet, d_out);
}

// Round 9
// 232.898 us; speedup vs baseline: 1.7404x; 1.0014x over previous
//
#include <hip/hip_runtime.h>
#include <stdint.h>

#define NN 20000
#define NE 200000
#define NG 128
#define NJOBS 6250   // 32-edge full-K jobs, one per wave
#define EGRID 1563   // ceil(6250/4) blocks
#define L2SLICE 410  // ceil(640000/1563) aggB-init elems per block

typedef __attribute__((ext_vector_type(8))) short short8;
typedef __attribute__((ext_vector_type(4))) float f32x4;
typedef __attribute__((ext_vector_type(4))) int   int4v;
typedef __attribute__((ext_vector_type(2))) unsigned int uint2v;

static __device__ __forceinline__ float bf2f(short s) {
    union { unsigned int u; float f; } x;
    x.u = ((unsigned int)(unsigned short)s) << 16;
    return x.f;
}
static __device__ __forceinline__ unsigned short f2bf(float f) {
    unsigned int u = __builtin_bit_cast(unsigned int, f);
    u += 0x7fffu + ((u >> 16) & 1u);
    return (unsigned short)(u >> 16);
}
// pack two floats into a dword of two bf16 (a low, b high): 2 add + 1 v_perm
static __device__ __forceinline__ unsigned int pack2bf(float a, float b) {
    unsigned int u0 = __builtin_bit_cast(unsigned int, a) + 0x8000u;
    unsigned int u1 = __builtin_bit_cast(unsigned int, b) + 0x8000u;
    return __builtin_amdgcn_perm(u1, u0, 0x07060302u);
}
// per-wave inline dtype detect: all lanes read x[0..63]; bf16 low-short exp
// field lands in [100,140] w.p. ~0.99 vs ~0.16 for fp32 mantissa bits.
static __device__ __forceinline__ int detect_isbf(const unsigned int* x) {
    unsigned int u = x[threadIdx.x & 63];
    unsigned int el = (u >> 7) & 0xffu;
    unsigned long long bm = __ballot((el >= 100u) && (el <= 140u));
    return __popcll(bm) > 32;
}

// ------------------------------------------------------------------ kernel 1:
// block-role split (all roles independent; all must precede edge1):
//   blocks [0,2500):    node embed + layer-1 root init (h0, aggA)
//   blocks [2500,4327): W2T transpose, w1t/b1f, pooled zero,
//                       ea -> bf16 workspace
//   blocks [4327,4952): zero aggB (for edge2's atomic-init of the root term)
__global__ __launch_bounds__(256) void k_prep_all(
    const void* x, const void* nfcw, const void* nfcb,
    const void* root1, const void* bias1,
    const void* w2a, const void* b2a, const void* w2b, const void* b2b,
    const void* w1a, const void* b1a, const void* w1b, const void* b1b,
    const void* ea,
    float* __restrict__ h0, float* __restrict__ aggA, float* __restrict__ aggB,
    short* __restrict__ W2Ta, short* __restrict__ W2Tb,
    short* __restrict__ w1t_ws, float* __restrict__ b1f_ws,
    float* __restrict__ pooled, short* __restrict__ ea_ws) {
    const int isbf = detect_isbf((const unsigned int*)x);
    const int b = blockIdx.x;

    if (b < 2500) {  // ---- role A: embed + aggA init ----
        __shared__ float wf[64 * 32];
        __shared__ float rf[32 * 32];
        __shared__ float bfs[32];
        __shared__ float rb[32];
        __shared__ float hrow[8][33];
        for (int i = threadIdx.x; i < 64 * 32; i += 256)
            wf[i] = isbf ? bf2f(((const short*)nfcw)[i]) : ((const float*)nfcw)[i];
        for (int i = threadIdx.x; i < 32 * 32; i += 256)
            rf[i] = isbf ? bf2f(((const short*)root1)[i]) : ((const float*)root1)[i];
        if (threadIdx.x < 32) {
            bfs[threadIdx.x] = isbf ? bf2f(((const short*)nfcb)[threadIdx.x])
                                    : ((const float*)nfcb)[threadIdx.x];
            rb[threadIdx.x]  = isbf ? bf2f(((const short*)bias1)[threadIdx.x])
                                    : ((const float*)bias1)[threadIdx.x];
        }
        __syncthreads();
        int t = b * 256 + threadIdx.x;
        int v = t >> 5, c = t & 31, vl = threadIdx.x >> 5;
        float acc = bfs[c];
        if (isbf) {
            const short* xr = (const short*)x + (size_t)v * 64;
#pragma unroll
            for (int q = 0; q < 64; ++q) acc += bf2f(xr[q]) * wf[q * 32 + c];
        } else {
            const float* xr = (const float*)x + (size_t)v * 64;
#pragma unroll
            for (int q = 0; q < 64; ++q) acc += xr[q] * wf[q * 32 + c];
        }
        float hv = acc > 0.f ? acc : 0.01f * acc;
        h0[t] = hv;
        hrow[vl][c] = hv;
        __syncthreads();
        float a2 = rb[c];
#pragma unroll
        for (int q = 0; q < 32; ++q) a2 += hrow[vl][q] * rf[q * 32 + c];
        aggA[t] = a2;
        return;
    }
    if (b < 4327) {  // ---- role B: weight prep ----
        const int bb = b - 2500;
        if (bb == 0) {
            for (int i = threadIdx.x; i < NG * 32; i += 256) pooled[i] = 0.f;
        }
        if (bb == 1) {
            for (int i = threadIdx.x; i < 1024; i += 256) {
                int layer = i >> 9, jj = i & 511, c = jj >> 4, q = jj & 15;
                const void* w1p = layer ? w1b : w1a;
                w1t_ws[i] = isbf ? ((const short*)w1p)[q * 32 + c]
                                 : (short)f2bf(((const float*)w1p)[q * 32 + c]);
            }
            for (int i = threadIdx.x; i < 64; i += 256) {
                int layer = i >> 5, c = i & 31;
                const void* b1p = layer ? b1b : b1a;
                b1f_ws[i] = isbf ? bf2f(((const short*)b1p)[c])
                                 : ((const float*)b1p)[c];
            }
        }
        int t = bb * 256 + threadIdx.x;
        if (t < 2 * 32 * 1056) {
            int layer = t / (32 * 1056);
            int r = t - layer * (32 * 1056);
            int o = r / 1056, kp = r - o * 1056;
            const void* w2 = layer ? w2b : w2a;
            const void* b2 = layer ? b2b : b2a;
            int idx; const void* sp;
            if (kp < 1024) { int kk = kp >> 5, i = kp & 31; idx = kk * 1024 + i * 32 + o; sp = w2; }
            else           { int i = kp - 1024;             idx = i * 32 + o;             sp = b2; }
            short v = isbf ? ((const short*)sp)[idx] : (short)f2bf(((const float*)sp)[idx]);
            (layer ? W2Tb : W2Ta)[o * 1056 + kp] = v;
            return;
        }
        int u = t - 2 * 32 * 1056;
        if (u < NE * 2 && !isbf) {  // 400000 threads x 8 elems
            const float* p = (const float*)ea + (size_t)u * 8;
            f32x4 f0 = *(const f32x4*)p;
            f32x4 f1 = *(const f32x4*)(p + 4);
            union { unsigned int d[4]; short8 v; } o8;
            o8.d[0] = pack2bf(f0[0], f0[1]);
            o8.d[1] = pack2bf(f0[2], f0[3]);
            o8.d[2] = pack2bf(f1[0], f1[1]);
            o8.d[3] = pack2bf(f1[2], f1[3]);
            *(short8*)&ea_ws[(size_t)u * 8] = o8.v;
        }
        return;
    }
    {  // ---- role C: zero aggB ----
        int idx = (b - 4327) * 256 + threadIdx.x;
        if (idx < NN * 32 / 4) {
            f32x4 z = {0.f, 0.f, 0.f, 0.f};
            ((f32x4*)aggB)[idx] = z;
        }
    }
}

// ------------------------------------------------------------------ edge kernel:
// FULL-K, one 32-edge job per wave, W2T read DIRECTLY from L2 (67.6KB hot,
// ~412MB/dispatch ~ 15TB/s aggregate, well under the 34.5TB/s L2 ceiling).
// -> atomics per edge-output pair happen ONCE (6.4M/dispatch, was 12.8M);
// ea/src/dst/h_in fetched once per edge; NO __syncthreads (h1 is per-wave
// LDS, 9.2KB/block); bank conflicts ~0 (h1 reads are same-addr broadcasts).
// Tests the 240G atomics/s wall theory cleanly at unchanged occupancy.
// layer2==1: block prologue atomically adds its 410-elem slice of
// aggB = lrelu(aggA)@root2 + bias2 (aggB pre-zeroed); gathered rows get
// lrelu inline.
__global__ __launch_bounds__(256, 4) void k_edge(
    const float* __restrict__ h_in,   // [N,32] fp32 (h0 or aggA)
    const short* __restrict__ W2T,    // [32][1056] bf16 (read via L2)
    const short* __restrict__ w1pre,  // [32 c][16 q] bf16 transposed (this layer)
    const float* __restrict__ b1pre,  // [32] fp32 (this layer)
    const int* __restrict__ src, const int* __restrict__ dst,
    const short* __restrict__ ea_bf,  // [E][16] bf16 (pre-converted or orig)
    const short* __restrict__ ea_ws,
    const unsigned int* xdet,
    float* agg,
    const int layer2, const void* rootp, const void* biasp) {
    __shared__ __align__(16) short h1l[4 * 32 * 36];  // per-wave [kk32][edge32+pad]

    const int isbf = detect_isbf(xdet);
    const short* eap = isbf ? ea_bf : ea_ws;

    if (layer2) {  // ---- fused k_mid: this block's slice of aggB root-init ----
        const int base = blockIdx.x * L2SLICE;
        for (int i = threadIdx.x; i < L2SLICE; i += 256) {
            int t = base + i;
            if (t < NN * 32) {
                int v = t >> 5, c = t & 31;
                const float* ar = h_in + (size_t)v * 32;
                float acc = isbf ? bf2f(((const short*)biasp)[c]) : ((const float*)biasp)[c];
#pragma unroll
                for (int q = 0; q < 32; ++q) {
                    float hv = ar[q];
                    hv = hv > 0.f ? hv : 0.01f * hv;
                    float wv = isbf ? bf2f(((const short*)rootp)[q * 32 + c])
                                    : ((const float*)rootp)[q * 32 + c];
                    acc += hv * wv;
                }
                atomicAdd(&agg[t], acc);
            }
        }
    }

    const int lane = threadIdx.x & 63;
    const int wid  = threadIdx.x >> 6;
    const int m    = lane & 15;
    const int quad = lane >> 4;
    const int wb   = wid * (32 * 36);

    const int j = blockIdx.x * 4 + wid;  // one job per wave
    if (j >= NJOBS) return;

    // B-fragments of w1 for kk=m and kk=m+16 (K padded 16->32, quads 2,3 zero)
    short8 w1lo = {0, 0, 0, 0, 0, 0, 0, 0};
    short8 w1hi = {0, 0, 0, 0, 0, 0, 0, 0};
    if (quad < 2) {
        w1lo = *(const short8*)&w1pre[m * 16 + ((quad & 1) << 3)];
        w1hi = *(const short8*)&w1pre[(m + 16) * 16 + ((quad & 1) << 3)];
    }
    const float b1lo = b1pre[m];
    const float b1hi = b1pre[m + 16];
    const f32x4 zero4 = {0.f, 0.f, 0.f, 0.f};

    // ---- prologue: all loads for this job ----
    const int e0 = j << 5;
    short8 eafc[2];
    f32x4 hs[2][2];
    int4v dv[2];
    {
        int s0[2];
#pragma unroll
        for (int mt = 0; mt < 2; ++mt) {
            eafc[mt] = *(const short8*)&eap[(size_t)(e0 + mt * 16 + m) * 16 + ((quad & 1) << 3)];
            s0[mt] = src[e0 + mt * 16 + m];
            dv[mt] = *(const int4v*)&dst[e0 + mt * 16 + (quad << 2)];
        }
#pragma unroll
        for (int mt = 0; mt < 2; ++mt) {
            const float* hr = h_in + (size_t)s0[mt] * 32 + (quad << 3);
            hs[mt][0] = *(const f32x4*)hr;
            hs[mt][1] = *(const f32x4*)(hr + 4);
        }
    }

    // ---- phase 1: h1 = relu(ea@w1+b1), all 32 kk -> bf16 [kk][edge] LDS ----
#pragma unroll
    for (int mt = 0; mt < 2; ++mt) {
        f32x4 alo = __builtin_amdgcn_mfma_f32_16x16x32_bf16(eafc[mt], w1lo, zero4, 0, 0, 0);
        f32x4 ahi = __builtin_amdgcn_mfma_f32_16x16x32_bf16(eafc[mt], w1hi, zero4, 0, 0, 0);
        float v0 = fmaxf(alo[0] + b1lo, 0.f);
        float v1 = fmaxf(alo[1] + b1lo, 0.f);
        float v2 = fmaxf(alo[2] + b1lo, 0.f);
        float v3 = fmaxf(alo[3] + b1lo, 0.f);
        uint2v dlo; dlo[0] = pack2bf(v0, v1); dlo[1] = pack2bf(v2, v3);
        // C/D: row(edge-local)=quad*4+r, col(kk)=m -> h1l[kk][mt*16+quad*4+r]
        *(uint2v*)&h1l[wb + m * 36 + (mt << 4) + (quad << 2)] = dlo;
        v0 = fmaxf(ahi[0] + b1hi, 0.f);
        v1 = fmaxf(ahi[1] + b1hi, 0.f);
        v2 = fmaxf(ahi[2] + b1hi, 0.f);
        v3 = fmaxf(ahi[3] + b1hi, 0.f);
        uint2v dhi; dhi[0] = pack2bf(v0, v1); dhi[1] = pack2bf(v2, v3);
        *(uint2v*)&h1l[wb + (m + 16) * 36 + (mt << 4) + (quad << 2)] = dhi;
    }
    __asm volatile("s_waitcnt lgkmcnt(0)" ::: "memory");

    // ---- convert hsrc -> bf16 A-fragment (lrelu inline for layer 2) ----
    short8 hsbf[2];
#pragma unroll
    for (int mt = 0; mt < 2; ++mt) {
        f32x4 g0 = hs[mt][0], g1 = hs[mt][1];
        if (layer2) {
#pragma unroll
            for (int p = 0; p < 4; ++p) {
                g0[p] = g0[p] > 0.f ? g0[p] : 0.01f * g0[p];
                g1[p] = g1[p] > 0.f ? g1[p] : 0.01f * g1[p];
            }
        }
        union { unsigned int du[4]; short8 v; } a;
        a.du[0] = pack2bf(g0[0], g0[1]);
        a.du[1] = pack2bf(g0[2], g0[3]);
        a.du[2] = pack2bf(g1[0], g1[1]);
        a.du[3] = pack2bf(g1[2], g1[3]);
        hsbf[mt] = a.v;
    }

    // ---- phase 2: 32 K-steps + bias step; B-fragments straight from L2 ----
    const short* wr0 = W2T + m * 1056 + (quad << 3);
    const short* wr1 = W2T + (m + 16) * 1056 + (quad << 3);
    f32x4 acc0[2] = {zero4, zero4}, acc1[2] = {zero4, zero4};
#pragma unroll
    for (int s = 0; s < 32; ++s) {
        short8 bf0 = *(const short8*)(wr0 + (s << 5));
        short8 bf1 = *(const short8*)(wr1 + (s << 5));
#pragma unroll
        for (int mt = 0; mt < 2; ++mt) {
            uint2v hd = *(const uint2v*)&h1l[wb + s * 36 + (mt << 4) + (quad << 2)];
            f32x4 hv;
            hv[0] = __builtin_bit_cast(float, hd[0] << 16);
            hv[1] = __builtin_bit_cast(float, hd[0] & 0xffff0000u);
            hv[2] = __builtin_bit_cast(float, hd[1] << 16);
            hv[3] = __builtin_bit_cast(float, hd[1] & 0xffff0000u);
            f32x4 u0 = __builtin_amdgcn_mfma_f32_16x16x32_bf16(hsbf[mt], bf0, zero4, 0, 0, 0);
            f32x4 u1 = __builtin_amdgcn_mfma_f32_16x16x32_bf16(hsbf[mt], bf1, zero4, 0, 0, 0);
            acc0[mt] += hv * u0;
            acc1[mt] += hv * u1;
        }
    }
    {  // bias block (kp 1024..1055, coefficient 1.0): MFMA direct into acc
        short8 bf0 = *(const short8*)(wr0 + 1024);
        short8 bf1 = *(const short8*)(wr1 + 1024);
#pragma unroll
        for (int mt = 0; mt < 2; ++mt) {
            acc0[mt] = __builtin_amdgcn_mfma_f32_16x16x32_bf16(hsbf[mt], bf0, acc0[mt], 0, 0, 0);
            acc1[mt] = __builtin_amdgcn_mfma_f32_16x16x32_bf16(hsbf[mt], bf1, acc1[mt], 0, 0, 0);
        }
    }

    // ---- epilogue: atomic scatter (32 per edge row -- ONCE per pair) ----
#pragma unroll
    for (int mt = 0; mt < 2; ++mt) {
#pragma unroll
        for (int r = 0; r < 4; ++r) {
            float* ap = agg + (size_t)dv[mt][r] * 32 + m;
            atomicAdd(ap, acc0[mt][r]);
            atomicAdd(ap + 16, acc1[mt][r]);
        }
    }
}

// ------------------------------------------------------------------ layer2 out
// LDS pre-aggregation of pooled: batch is sorted, so an 8-node block spans
// ~1-2 graphs -> global atomics drop 640k -> ~10k.
__global__ __launch_bounds__(256) void k_final_nodes(
    const float* __restrict__ agg, const int* __restrict__ batch,
    const unsigned int* xdet, void* __restrict__ out, float* pooled) {
    const int isbf = detect_isbf(xdet);
    __shared__ float gacc[8][32];
    __shared__ int g0s;
    ((float*)gacc)[threadIdx.x] = 0.f;
    if (threadIdx.x == 0) g0s = batch[blockIdx.x * 8];
    __syncthreads();
    int t = blockIdx.x * 256 + threadIdx.x;
    float v = agg[t];
    v = v > 0.f ? v : 0.01f * v;
    if (isbf) ((short*)out)[4096 + t] = (short)f2bf(v);
    else      ((float*)out)[4096 + t] = v;
    int g = batch[t >> 5];
    int rel = g - g0s;
    int c = t & 31;
    if (rel < 8) atomicAdd(&gacc[rel][c], v);
    else         atomicAdd(&pooled[g * 32 + c], v);
    __syncthreads();
    {
        int gi = threadIdx.x >> 5, cc = threadIdx.x & 31;
        float s = gacc[gi][cc];
        if (s != 0.f) atomicAdd(&pooled[(g0s + gi) * 32 + cc], s);
    }
}

// ------------------------------------------------------------------ graph head
__global__ __launch_bounds__(64) void k_graph_out(
    const float* __restrict__ pooled, const void* fcw, const void* fcb,
    const unsigned int* xdet, void* __restrict__ out) {
    const int isbf = detect_isbf(xdet);
    int g = blockIdx.x;
    int t = threadIdx.x;
    __shared__ float pn[32];
    if (t < 32) {
        float p = pooled[g * 32 + t];
        float sq = p * p;
#pragma unroll
        for (int o = 16; o > 0; o >>= 1) sq += __shfl_xor(sq, o, 64);
        float inv = 1.0f / fmaxf(sqrtf(sq), 1e-12f);
        pn[t] = p * inv;
    }
    __syncthreads();
    if (t < 32) {
        float acc = isbf ? bf2f(((const short*)fcb)[t]) : ((const float*)fcb)[t];
#pragma unroll
        for (int q = 0; q < 32; ++q) {
            float wv = isbf ? bf2f(((const short*)fcw)[q * 32 + t])
                            : ((const float*)fcw)[q * 32 + t];
            acc += pn[q] * wv;
        }
        if (isbf) ((short*)out)[g * 32 + t] = (short)f2bf(acc);
        else      ((float*)out)[g * 32 + t] = acc;
    }
}

extern "C" void kernel_launch(void* const* d_in, const int* in_sizes, int n_in,
                              void* d_out, int out_size, void* d_ws, size_t ws_size,
                              hipStream_t stream) {
    (void)in_sizes; (void)n_in; (void)out_size; (void)ws_size;
    const void* x     = d_in[0];
    const int*  eidx  = (const int*)d_in[1];
    const void* ea    = d_in[2];
    const int*  batch = (const int*)d_in[3];
    const void* nfcw  = d_in[5];
    const void* nfcb  = d_in[6];
    const void* e1w1  = d_in[7];
    const void* e1b1  = d_in[8];
    const void* e1w2  = d_in[9];
    const void* e1b2  = d_in[10];
    const void* root1 = d_in[11];
    const void* bias1 = d_in[12];
    const void* e2w1  = d_in[13];
    const void* e2b1  = d_in[14];
    const void* e2w2  = d_in[15];
    const void* e2b2  = d_in[16];
    const void* root2 = d_in[17];
    const void* bias2 = d_in[18];
    const void* fcw   = d_in[19];
    const void* fcb   = d_in[20];
    const unsigned int* xdet = (const unsigned int*)x;

    char* ws = (char*)d_ws;
    float* h0     = (float*)ws; ws += (size_t)NN * 32 * 4;
    float* aggA   = (float*)ws; ws += (size_t)NN * 32 * 4;
    float* aggB   = (float*)ws; ws += (size_t)NN * 32 * 4;
    short* W2T1   = (short*)ws; ws += 32 * 1056 * 2;
    short* W2T2   = (short*)ws; ws += 32 * 1056 * 2;
    short* w1t_ws = (short*)ws; ws += 1024 * 2;
    float* b1f_ws = (float*)ws; ws += 64 * 4;
    float* pooled = (float*)ws; ws += NG * 32 * 4;
    short* ea_ws  = (short*)ws; ws += (size_t)NE * 16 * 2;

    const int* srcp = eidx;
    const int* dstp = eidx + NE;

    // kernel 1: embed(2500) + prep(1827) + aggB-zero(625) = 4952 blocks
    k_prep_all<<<4952, 256, 0, stream>>>(
        x, nfcw, nfcb, root1, bias1,
        e1w2, e1b2, e2w2, e2b2, e1w1, e1b1, e2w1, e2b1, ea,
        h0, aggA, aggB, W2T1, W2T2, w1t_ws, b1f_ws, pooled, ea_ws);

    // layer 1 (full-K, one job per wave)
    k_edge<<<EGRID, 256, 0, stream>>>(h0, W2T1, w1t_ws, b1f_ws, srcp, dstp,
                                      (const short*)ea, ea_ws, xdet, aggA,
                                      0, nullptr, nullptr);
    // layer 2 (fused root2-init + inline lrelu on gathered aggA)
    k_edge<<<EGRID, 256, 0, stream>>>(aggA, W2T2, w1t_ws + 512, b1f_ws + 32, srcp, dstp,
                                      (const short*)ea, ea_ws, xdet, aggB,
                                      1, root2, bias2);
    // node output + pooled
    k_final_nodes<<<(NN * 32 + 255) / 256, 256, 0, stream>>>(aggB, batch, xdet, d_out, pooled);
    // graph head
    k_graph_out<<<NG, 64, 0, stream>>>(pooled, fcw, fcb, xdet, d_out);
}

// Round 10
// 222.469 us; speedup vs baseline: 1.8220x; 1.0469x over previous
//
#include <hip/hip_runtime.h>
#include <stdint.h>

#define NN 20000
#define NE 200000
#define NG 128
#define NWJOBS 3125  // 64-edge full-K jobs, one per wave
#define EGRID 782    // ceil(3125/4) blocks
#define L2SLICE 819  // ceil(640000/782) aggB-init elems per block

typedef __attribute__((ext_vector_type(8))) short short8;
typedef __attribute__((ext_vector_type(4))) float f32x4;
typedef __attribute__((ext_vector_type(4))) int   int4v;
typedef __attribute__((ext_vector_type(2))) unsigned int uint2v;

static __device__ __forceinline__ float bf2f(short s) {
    union { unsigned int u; float f; } x;
    x.u = ((unsigned int)(unsigned short)s) << 16;
    return x.f;
}
static __device__ __forceinline__ unsigned short f2bf(float f) {
    unsigned int u = __builtin_bit_cast(unsigned int, f);
    u += 0x7fffu + ((u >> 16) & 1u);
    return (unsigned short)(u >> 16);
}
// pack two floats into a dword of two bf16 (a low, b high): 2 add + 1 v_perm
static __device__ __forceinline__ unsigned int pack2bf(float a, float b) {
    unsigned int u0 = __builtin_bit_cast(unsigned int, a) + 0x8000u;
    unsigned int u1 = __builtin_bit_cast(unsigned int, b) + 0x8000u;
    return __builtin_amdgcn_perm(u1, u0, 0x07060302u);
}
// per-wave inline dtype detect: all lanes read x[0..63]; bf16 low-short exp
// field lands in [100,140] w.p. ~0.99 vs ~0.16 for fp32 mantissa bits.
static __device__ __forceinline__ int detect_isbf(const unsigned int* x) {
    unsigned int u = x[threadIdx.x & 63];
    unsigned int el = (u >> 7) & 0xffu;
    unsigned long long bm = __ballot((el >= 100u) && (el <= 140u));
    return __popcll(bm) > 32;
}

// ------------------------------------------------------------------ kernel 1:
// block-role split (all roles independent; all must precede edge1):
//   blocks [0,2500):    node embed + layer-1 root init (h0, aggA)
//   blocks [2500,4327): W2T transpose, w1t/b1f, pooled zero,
//                       ea -> bf16 workspace
//   blocks [4327,4952): zero aggB (for edge2's atomic-init of the root term)
__global__ __launch_bounds__(256) void k_prep_all(
    const void* x, const void* nfcw, const void* nfcb,
    const void* root1, const void* bias1,
    const void* w2a, const void* b2a, const void* w2b, const void* b2b,
    const void* w1a, const void* b1a, const void* w1b, const void* b1b,
    const void* ea,
    float* __restrict__ h0, float* __restrict__ aggA, float* __restrict__ aggB,
    short* __restrict__ W2Ta, short* __restrict__ W2Tb,
    short* __restrict__ w1t_ws, float* __restrict__ b1f_ws,
    float* __restrict__ pooled, short* __restrict__ ea_ws) {
    const int isbf = detect_isbf((const unsigned int*)x);
    const int b = blockIdx.x;

    if (b < 2500) {  // ---- role A: embed + aggA init (vectorized x loads) ----
        __shared__ float wf[64 * 32];
        __shared__ float rf[32 * 32];
        __shared__ float bfs[32];
        __shared__ float rb[32];
        __shared__ float xrow[8][66];   // staged x rows, fp32
        __shared__ float hrow[8][33];
        for (int i = threadIdx.x; i < 64 * 32; i += 256)
            wf[i] = isbf ? bf2f(((const short*)nfcw)[i]) : ((const float*)nfcw)[i];
        for (int i = threadIdx.x; i < 32 * 32; i += 256)
            rf[i] = isbf ? bf2f(((const short*)root1)[i]) : ((const float*)root1)[i];
        if (threadIdx.x < 32) {
            bfs[threadIdx.x] = isbf ? bf2f(((const short*)nfcb)[threadIdx.x])
                                    : ((const float*)nfcb)[threadIdx.x];
            rb[threadIdx.x]  = isbf ? bf2f(((const short*)bias1)[threadIdx.x])
                                    : ((const float*)bias1)[threadIdx.x];
        }
        int t = b * 256 + threadIdx.x;
        int v = t >> 5, c = t & 31, vl = threadIdx.x >> 5;
        // coalesced row staging: 32 threads load the row's 64 values
        if (isbf) {
            const short* xr = (const short*)x + (size_t)v * 64;
            xrow[vl][c]      = bf2f(xr[c]);
            xrow[vl][32 + c] = bf2f(xr[32 + c]);
        } else {
            const float* xr = (const float*)x + (size_t)v * 64;
            xrow[vl][c]      = xr[c];
            xrow[vl][32 + c] = xr[32 + c];
        }
        __syncthreads();
        float acc = bfs[c];
#pragma unroll
        for (int q = 0; q < 64; ++q) acc += xrow[vl][q] * wf[q * 32 + c];
        float hv = acc > 0.f ? acc : 0.01f * acc;
        h0[t] = hv;
        hrow[vl][c] = hv;
        __syncthreads();
        float a2 = rb[c];
#pragma unroll
        for (int q = 0; q < 32; ++q) a2 += hrow[vl][q] * rf[q * 32 + c];
        aggA[t] = a2;
        return;
    }
    if (b < 4327) {  // ---- role B: weight prep ----
        const int bb = b - 2500;
        if (bb == 0) {
            for (int i = threadIdx.x; i < NG * 32; i += 256) pooled[i] = 0.f;
        }
        if (bb == 1) {
            for (int i = threadIdx.x; i < 1024; i += 256) {
                int layer = i >> 9, jj = i & 511, c = jj >> 4, q = jj & 15;
                const void* w1p = layer ? w1b : w1a;
                w1t_ws[i] = isbf ? ((const short*)w1p)[q * 32 + c]
                                 : (short)f2bf(((const float*)w1p)[q * 32 + c]);
            }
            for (int i = threadIdx.x; i < 64; i += 256) {
                int layer = i >> 5, c = i & 31;
                const void* b1p = layer ? b1b : b1a;
                b1f_ws[i] = isbf ? bf2f(((const short*)b1p)[c])
                                 : ((const float*)b1p)[c];
            }
        }
        int t = bb * 256 + threadIdx.x;
        if (t < 2 * 32 * 1056) {
            int layer = t / (32 * 1056);
            int r = t - layer * (32 * 1056);
            int o = r / 1056, kp = r - o * 1056;
            const void* w2 = layer ? w2b : w2a;
            const void* b2 = layer ? b2b : b2a;
            int idx; const void* sp;
            if (kp < 1024) { int kk = kp >> 5, i = kp & 31; idx = kk * 1024 + i * 32 + o; sp = w2; }
            else           { int i = kp - 1024;             idx = i * 32 + o;             sp = b2; }
            short v = isbf ? ((const short*)sp)[idx] : (short)f2bf(((const float*)sp)[idx]);
            (layer ? W2Tb : W2Ta)[o * 1056 + kp] = v;
            return;
        }
        int u = t - 2 * 32 * 1056;
        if (u < NE * 2 && !isbf) {  // 400000 threads x 8 elems
            const float* p = (const float*)ea + (size_t)u * 8;
            f32x4 f0 = *(const f32x4*)p;
            f32x4 f1 = *(const f32x4*)(p + 4);
            union { unsigned int d[4]; short8 v; } o8;
            o8.d[0] = pack2bf(f0[0], f0[1]);
            o8.d[1] = pack2bf(f0[2], f0[3]);
            o8.d[2] = pack2bf(f1[0], f1[1]);
            o8.d[3] = pack2bf(f1[2], f1[3]);
            *(short8*)&ea_ws[(size_t)u * 8] = o8.v;
        }
        return;
    }
    {  // ---- role C: zero aggB ----
        int idx = (b - 4327) * 256 + threadIdx.x;
        if (idx < NN * 32 / 4) {
            f32x4 z = {0.f, 0.f, 0.f, 0.f};
            ((f32x4*)aggB)[idx] = z;
        }
    }
}

// ------------------------------------------------------------------ edge kernel:
// FULL-K, 64 edges (2 jobs) per wave in ONE pass over W2T: per K-step the
// bf0/bf1 L2 loads are shared by 4 edge-group MFMAs -> W2T L2 transactions
// halve vs r9 (6.6M -> 3.3M/dispatch), which the transaction model says is
// the binding resource.  Atomics stay halved (full-K, once per edge-output),
// no __syncthreads in the job path, h1 per-wave LDS (broadcast reads, 0
// conflicts).  LDS 17.4KB; VGPR target <=128 -> 4 blocks/CU; 782 blocks ->
// all resident.
// layer2==1: block prologue atomically adds its slice of
// aggB = lrelu(aggA)@root2 + bias2 (aggB pre-zeroed); gathered rows get
// lrelu inline.
__global__ __launch_bounds__(256, 4) void k_edge(
    const float* __restrict__ h_in,   // [N,32] fp32 (h0 or aggA)
    const short* __restrict__ W2T,    // [32][1056] bf16 (read via L2)
    const short* __restrict__ w1pre,  // [32 c][16 q] bf16 transposed (this layer)
    const float* __restrict__ b1pre,  // [32] fp32 (this layer)
    const int* __restrict__ src, const int* __restrict__ dst,
    const short* __restrict__ ea_bf,  // [E][16] bf16 (pre-converted or orig)
    const short* __restrict__ ea_ws,
    const unsigned int* xdet,
    float* agg,
    const int layer2, const void* rootp, const void* biasp) {
    __shared__ __align__(16) short h1l[4 * 32 * 68];  // per-wave [kk32][edge64+pad]

    const int isbf = detect_isbf(xdet);
    const short* eap = isbf ? ea_bf : ea_ws;

    if (layer2) {  // ---- fused k_mid: this block's slice of aggB root-init ----
        const int base = blockIdx.x * L2SLICE;
        for (int i = threadIdx.x; i < L2SLICE; i += 256) {
            int t = base + i;
            if (t < NN * 32) {
                int v = t >> 5, c = t & 31;
                const float* ar = h_in + (size_t)v * 32;
                float acc = isbf ? bf2f(((const short*)biasp)[c]) : ((const float*)biasp)[c];
#pragma unroll
                for (int q = 0; q < 32; ++q) {
                    float hv = ar[q];
                    hv = hv > 0.f ? hv : 0.01f * hv;
                    float wv = isbf ? bf2f(((const short*)rootp)[q * 32 + c])
                                    : ((const float*)rootp)[q * 32 + c];
                    acc += hv * wv;
                }
                atomicAdd(&agg[t], acc);
            }
        }
    }

    const int lane = threadIdx.x & 63;
    const int wid  = threadIdx.x >> 6;
    const int m    = lane & 15;
    const int quad = lane >> 4;
    const int wb   = wid * (32 * 68);

    const int w = blockIdx.x * 4 + wid;  // one 64-edge job per wave
    if (w >= NWJOBS) return;

    // B-fragments of w1 for kk=m and kk=m+16 (K padded 16->32, quads 2,3 zero)
    short8 w1lo = {0, 0, 0, 0, 0, 0, 0, 0};
    short8 w1hi = {0, 0, 0, 0, 0, 0, 0, 0};
    if (quad < 2) {
        w1lo = *(const short8*)&w1pre[m * 16 + ((quad & 1) << 3)];
        w1hi = *(const short8*)&w1pre[(m + 16) * 16 + ((quad & 1) << 3)];
    }
    const float b1lo = b1pre[m];
    const float b1hi = b1pre[m + 16];
    const f32x4 zero4 = {0.f, 0.f, 0.f, 0.f};

    // ---- prologue: all loads for the 64 edges ----
    const int e0 = w << 6;
    short8 eafc[4];
    f32x4 hs[4][2];
    int4v dv[4];
    {
        int s0[4];
#pragma unroll
        for (int mt = 0; mt < 4; ++mt) {
            eafc[mt] = *(const short8*)&eap[(size_t)(e0 + mt * 16 + m) * 16 + ((quad & 1) << 3)];
            s0[mt] = src[e0 + mt * 16 + m];
            dv[mt] = *(const int4v*)&dst[e0 + mt * 16 + (quad << 2)];
        }
#pragma unroll
        for (int mt = 0; mt < 4; ++mt) {
            const float* hr = h_in + (size_t)s0[mt] * 32 + (quad << 3);
            hs[mt][0] = *(const f32x4*)hr;
            hs[mt][1] = *(const f32x4*)(hr + 4);
        }
    }

    // ---- phase 1: h1 = relu(ea@w1+b1), all 32 kk -> bf16 [kk][edge] LDS ----
#pragma unroll
    for (int mt = 0; mt < 4; ++mt) {
        f32x4 alo = __builtin_amdgcn_mfma_f32_16x16x32_bf16(eafc[mt], w1lo, zero4, 0, 0, 0);
        f32x4 ahi = __builtin_amdgcn_mfma_f32_16x16x32_bf16(eafc[mt], w1hi, zero4, 0, 0, 0);
        float v0 = fmaxf(alo[0] + b1lo, 0.f);
        float v1 = fmaxf(alo[1] + b1lo, 0.f);
        float v2 = fmaxf(alo[2] + b1lo, 0.f);
        float v3 = fmaxf(alo[3] + b1lo, 0.f);
        uint2v dlo; dlo[0] = pack2bf(v0, v1); dlo[1] = pack2bf(v2, v3);
        // C/D: row(edge-local)=quad*4+r, col(kk)=m -> h1l[kk][mt*16+quad*4+r]
        *(uint2v*)&h1l[wb + m * 68 + (mt << 4) + (quad << 2)] = dlo;
        v0 = fmaxf(ahi[0] + b1hi, 0.f);
        v1 = fmaxf(ahi[1] + b1hi, 0.f);
        v2 = fmaxf(ahi[2] + b1hi, 0.f);
        v3 = fmaxf(ahi[3] + b1hi, 0.f);
        uint2v dhi; dhi[0] = pack2bf(v0, v1); dhi[1] = pack2bf(v2, v3);
        *(uint2v*)&h1l[wb + (m + 16) * 68 + (mt << 4) + (quad << 2)] = dhi;
    }
    __asm volatile("s_waitcnt lgkmcnt(0)" ::: "memory");

    // ---- convert hsrc -> bf16 A-fragment (lrelu inline for layer 2) ----
    short8 hsbf[4];
#pragma unroll
    for (int mt = 0; mt < 4; ++mt) {
        f32x4 g0 = hs[mt][0], g1 = hs[mt][1];
        if (layer2) {
#pragma unroll
            for (int p = 0; p < 4; ++p) {
                g0[p] = g0[p] > 0.f ? g0[p] : 0.01f * g0[p];
                g1[p] = g1[p] > 0.f ? g1[p] : 0.01f * g1[p];
            }
        }
        union { unsigned int du[4]; short8 v; } a;
        a.du[0] = pack2bf(g0[0], g0[1]);
        a.du[1] = pack2bf(g0[2], g0[3]);
        a.du[2] = pack2bf(g1[0], g1[1]);
        a.du[3] = pack2bf(g1[2], g1[3]);
        hsbf[mt] = a.v;
    }

    // ---- phase 2: 32 K-steps + bias; each bf0/bf1 load feeds 4 edge groups ----
    const short* wr0 = W2T + m * 1056 + (quad << 3);
    const short* wr1 = W2T + (m + 16) * 1056 + (quad << 3);
    f32x4 acc0[4] = {zero4, zero4, zero4, zero4};
    f32x4 acc1[4] = {zero4, zero4, zero4, zero4};
#pragma unroll
    for (int s = 0; s < 32; ++s) {
        short8 bf0 = *(const short8*)(wr0 + (s << 5));
        short8 bf1 = *(const short8*)(wr1 + (s << 5));
#pragma unroll
        for (int mt = 0; mt < 4; ++mt) {
            uint2v hd = *(const uint2v*)&h1l[wb + s * 68 + (mt << 4) + (quad << 2)];
            f32x4 hv;
            hv[0] = __builtin_bit_cast(float, hd[0] << 16);
            hv[1] = __builtin_bit_cast(float, hd[0] & 0xffff0000u);
            hv[2] = __builtin_bit_cast(float, hd[1] << 16);
            hv[3] = __builtin_bit_cast(float, hd[1] & 0xffff0000u);
            f32x4 u0 = __builtin_amdgcn_mfma_f32_16x16x32_bf16(hsbf[mt], bf0, zero4, 0, 0, 0);
            f32x4 u1 = __builtin_amdgcn_mfma_f32_16x16x32_bf16(hsbf[mt], bf1, zero4, 0, 0, 0);
            acc0[mt] += hv * u0;
            acc1[mt] += hv * u1;
        }
    }
    {  // bias block (kp 1024..1055, coefficient 1.0): MFMA direct into acc
        short8 bf0 = *(const short8*)(wr0 + 1024);
        short8 bf1 = *(const short8*)(wr1 + 1024);
#pragma unroll
        for (int mt = 0; mt < 4; ++mt) {
            acc0[mt] = __builtin_amdgcn_mfma_f32_16x16x32_bf16(hsbf[mt], bf0, acc0[mt], 0, 0, 0);
            acc1[mt] = __builtin_amdgcn_mfma_f32_16x16x32_bf16(hsbf[mt], bf1, acc1[mt], 0, 0, 0);
        }
    }

    // ---- epilogue: atomic scatter (32 per edge row -- ONCE per pair) ----
#pragma unroll
    for (int mt = 0; mt < 4; ++mt) {
#pragma unroll
        for (int r = 0; r < 4; ++r) {
            float* ap = agg + (size_t)dv[mt][r] * 32 + m;
            atomicAdd(ap, acc0[mt][r]);
            atomicAdd(ap + 16, acc1[mt][r]);
        }
    }
}

// ------------------------------------------------------------------ layer2 out
// LDS pre-aggregation of pooled: batch is sorted, so an 8-node block spans
// ~1-2 graphs -> global atomics drop 640k -> ~10k.
__global__ __launch_bounds__(256) void k_final_nodes(
    const float* __restrict__ agg, const int* __restrict__ batch,
    const unsigned int* xdet, void* __restrict__ out, float* pooled) {
    const int isbf = detect_isbf(xdet);
    __shared__ float gacc[8][32];
    __shared__ int g0s;
    ((float*)gacc)[threadIdx.x] = 0.f;
    if (threadIdx.x == 0) g0s = batch[blockIdx.x * 8];
    __syncthreads();
    int t = blockIdx.x * 256 + threadIdx.x;
    float v = agg[t];
    v = v > 0.f ? v : 0.01f * v;
    if (isbf) ((short*)out)[4096 + t] = (short)f2bf(v);
    else      ((float*)out)[4096 + t] = v;
    int g = batch[t >> 5];
    int rel = g - g0s;
    int c = t & 31;
    if (rel < 8) atomicAdd(&gacc[rel][c], v);
    else         atomicAdd(&pooled[g * 32 + c], v);
    __syncthreads();
    {
        int gi = threadIdx.x >> 5, cc = threadIdx.x & 31;
        float s = gacc[gi][cc];
        if (s != 0.f) atomicAdd(&pooled[(g0s + gi) * 32 + cc], s);
    }
}

// ------------------------------------------------------------------ graph head
__global__ __launch_bounds__(64) void k_graph_out(
    const float* __restrict__ pooled, const void* fcw, const void* fcb,
    const unsigned int* xdet, void* __restrict__ out) {
    const int isbf = detect_isbf(xdet);
    int g = blockIdx.x;
    int t = threadIdx.x;
    __shared__ float pn[32];
    if (t < 32) {
        float p = pooled[g * 32 + t];
        float sq = p * p;
#pragma unroll
        for (int o = 16; o > 0; o >>= 1) sq += __shfl_xor(sq, o, 64);
        float inv = 1.0f / fmaxf(sqrtf(sq), 1e-12f);
        pn[t] = p * inv;
    }
    __syncthreads();
    if (t < 32) {
        float acc = isbf ? bf2f(((const short*)fcb)[t]) : ((const float*)fcb)[t];
#pragma unroll
        for (int q = 0; q < 32; ++q) {
            float wv = isbf ? bf2f(((const short*)fcw)[q * 32 + t])
                            : ((const float*)fcw)[q * 32 + t];
            acc += pn[q] * wv;
        }
        if (isbf) ((short*)out)[g * 32 + t] = (short)f2bf(acc);
        else      ((float*)out)[g * 32 + t] = acc;
    }
}

extern "C" void kernel_launch(void* const* d_in, const int* in_sizes, int n_in,
                              void* d_out, int out_size, void* d_ws, size_t ws_size,
                              hipStream_t stream) {
    (void)in_sizes; (void)n_in; (void)out_size; (void)ws_size;
    const void* x     = d_in[0];
    const int*  eidx  = (const int*)d_in[1];
    const void* ea    = d_in[2];
    const int*  batch = (const int*)d_in[3];
    const void* nfcw  = d_in[5];
    const void* nfcb  = d_in[6];
    const void* e1w1  = d_in[7];
    const void* e1b1  = d_in[8];
    const void* e1w2  = d_in[9];
    const void* e1b2  = d_in[10];
    const void* root1 = d_in[11];
    const void* bias1 = d_in[12];
    const void* e2w1  = d_in[13];
    const void* e2b1  = d_in[14];
    const void* e2w2  = d_in[15];
    const void* e2b2  = d_in[16];
    const void* root2 = d_in[17];
    const void* bias2 = d_in[18];
    const void* fcw   = d_in[19];
    const void* fcb   = d_in[20];
    const unsigned int* xdet = (const unsigned int*)x;

    char* ws = (char*)d_ws;
    float* h0     = (float*)ws; ws += (size_t)NN * 32 * 4;
    float* aggA   = (float*)ws; ws += (size_t)NN * 32 * 4;
    float* aggB   = (float*)ws; ws += (size_t)NN * 32 * 4;
    short* W2T1   = (short*)ws; ws += 32 * 1056 * 2;
    short* W2T2   = (short*)ws; ws += 32 * 1056 * 2;
    short* w1t_ws = (short*)ws; ws += 1024 * 2;
    float* b1f_ws = (float*)ws; ws += 64 * 4;
    float* pooled = (float*)ws; ws += NG * 32 * 4;
    short* ea_ws  = (short*)ws; ws += (size_t)NE * 16 * 2;

    const int* srcp = eidx;
    const int* dstp = eidx + NE;

    // kernel 1: embed(2500) + prep(1827) + aggB-zero(625) = 4952 blocks
    k_prep_all<<<4952, 256, 0, stream>>>(
        x, nfcw, nfcb, root1, bias1,
        e1w2, e1b2, e2w2, e2b2, e1w1, e1b1, e2w1, e2b1, ea,
        h0, aggA, aggB, W2T1, W2T2, w1t_ws, b1f_ws, pooled, ea_ws);

    // layer 1 (full-K, 64 edges per wave)
    k_edge<<<EGRID, 256, 0, stream>>>(h0, W2T1, w1t_ws, b1f_ws, srcp, dstp,
                                      (const short*)ea, ea_ws, xdet, aggA,
                                      0, nullptr, nullptr);
    // layer 2 (fused root2-init + inline lrelu on gathered aggA)
    k_edge<<<EGRID, 256, 0, stream>>>(aggA, W2T2, w1t_ws + 512, b1f_ws + 32, srcp, dstp,
                                      (const short*)ea, ea_ws, xdet, aggB,
                                      1, root2, bias2);
    // node output + pooled
    k_final_nodes<<<(NN * 32 + 255) / 256, 256, 0, stream>>>(aggB, batch, xdet, d_out, pooled);
    // graph head
    k_graph_out<<<NG, 64, 0, stream>>>(pooled, fcw, fcb, xdet, d_out);
}

// Round 11
// 218.519 us; speedup vs baseline: 1.8549x; 1.0181x over previous
//
#include <hip/hip_runtime.h>
#include <stdint.h>

#define NN 20000
#define NE 200000
#define NG 128
#define NWJOBS 3125  // 64-edge full-K jobs, one per wave
#define EGRID 782    // ceil(3125/4) blocks
#define L2SLICE 819  // ceil(640000/782) aggB-init elems per block

typedef __attribute__((ext_vector_type(8))) short short8;
typedef __attribute__((ext_vector_type(4))) float f32x4;
typedef __attribute__((ext_vector_type(4))) int   int4v;
typedef __attribute__((ext_vector_type(2))) unsigned int uint2v;

static __device__ __forceinline__ float bf2f(short s) {
    union { unsigned int u; float f; } x;
    x.u = ((unsigned int)(unsigned short)s) << 16;
    return x.f;
}
static __device__ __forceinline__ unsigned short f2bf(float f) {
    unsigned int u = __builtin_bit_cast(unsigned int, f);
    u += 0x7fffu + ((u >> 16) & 1u);
    return (unsigned short)(u >> 16);
}
// pack two floats into a dword of two bf16 (a low, b high): 2 add + 1 v_perm
static __device__ __forceinline__ unsigned int pack2bf(float a, float b) {
    unsigned int u0 = __builtin_bit_cast(unsigned int, a) + 0x8000u;
    unsigned int u1 = __builtin_bit_cast(unsigned int, b) + 0x8000u;
    return __builtin_amdgcn_perm(u1, u0, 0x07060302u);
}
// per-wave inline dtype detect: all lanes read x[0..63]; bf16 low-short exp
// field lands in [100,140] w.p. ~0.99 vs ~0.16 for fp32 mantissa bits.
static __device__ __forceinline__ int detect_isbf(const unsigned int* x) {
    unsigned int u = x[threadIdx.x & 63];
    unsigned int el = (u >> 7) & 0xffu;
    unsigned long long bm = __ballot((el >= 100u) && (el <= 140u));
    return __popcll(bm) > 32;
}

// ------------------------------------------------------------------ kernel 1:
// block-role split (all roles independent; all must precede edge1):
//   blocks [0,2500):    node embed + layer-1 root init (h0, aggA)
//   blocks [2500,4327): W2T transpose, w1t/b1f, ea -> bf16 workspace
//   blocks [4327,4952): zero aggB (for edge2's atomic-init of the root term)
__global__ __launch_bounds__(256) void k_prep_all(
    const void* x, const void* nfcw, const void* nfcb,
    const void* root1, const void* bias1,
    const void* w2a, const void* b2a, const void* w2b, const void* b2b,
    const void* w1a, const void* b1a, const void* w1b, const void* b1b,
    const void* ea,
    float* __restrict__ h0, float* __restrict__ aggA, float* __restrict__ aggB,
    short* __restrict__ W2Ta, short* __restrict__ W2Tb,
    short* __restrict__ w1t_ws, float* __restrict__ b1f_ws,
    short* __restrict__ ea_ws) {
    const int isbf = detect_isbf((const unsigned int*)x);
    const int b = blockIdx.x;

    if (b < 2500) {  // ---- role A: embed + aggA init (vectorized x loads) ----
        __shared__ float wf[64 * 32];
        __shared__ float rf[32 * 32];
        __shared__ float bfs[32];
        __shared__ float rb[32];
        __shared__ float xrow[8][66];   // staged x rows, fp32
        __shared__ float hrow[8][33];
        for (int i = threadIdx.x; i < 64 * 32; i += 256)
            wf[i] = isbf ? bf2f(((const short*)nfcw)[i]) : ((const float*)nfcw)[i];
        for (int i = threadIdx.x; i < 32 * 32; i += 256)
            rf[i] = isbf ? bf2f(((const short*)root1)[i]) : ((const float*)root1)[i];
        if (threadIdx.x < 32) {
            bfs[threadIdx.x] = isbf ? bf2f(((const short*)nfcb)[threadIdx.x])
                                    : ((const float*)nfcb)[threadIdx.x];
            rb[threadIdx.x]  = isbf ? bf2f(((const short*)bias1)[threadIdx.x])
                                    : ((const float*)bias1)[threadIdx.x];
        }
        int t = b * 256 + threadIdx.x;
        int v = t >> 5, c = t & 31, vl = threadIdx.x >> 5;
        // coalesced row staging: 32 threads load the row's 64 values
        if (isbf) {
            const short* xr = (const short*)x + (size_t)v * 64;
            xrow[vl][c]      = bf2f(xr[c]);
            xrow[vl][32 + c] = bf2f(xr[32 + c]);
        } else {
            const float* xr = (const float*)x + (size_t)v * 64;
            xrow[vl][c]      = xr[c];
            xrow[vl][32 + c] = xr[32 + c];
        }
        __syncthreads();
        float acc = bfs[c];
#pragma unroll
        for (int q = 0; q < 64; ++q) acc += xrow[vl][q] * wf[q * 32 + c];
        float hv = acc > 0.f ? acc : 0.01f * acc;
        h0[t] = hv;
        hrow[vl][c] = hv;
        __syncthreads();
        float a2 = rb[c];
#pragma unroll
        for (int q = 0; q < 32; ++q) a2 += hrow[vl][q] * rf[q * 32 + c];
        aggA[t] = a2;
        return;
    }
    if (b < 4327) {  // ---- role B: weight prep ----
        const int bb = b - 2500;
        if (bb == 1) {
            for (int i = threadIdx.x; i < 1024; i += 256) {
                int layer = i >> 9, jj = i & 511, c = jj >> 4, q = jj & 15;
                const void* w1p = layer ? w1b : w1a;
                w1t_ws[i] = isbf ? ((const short*)w1p)[q * 32 + c]
                                 : (short)f2bf(((const float*)w1p)[q * 32 + c]);
            }
            for (int i = threadIdx.x; i < 64; i += 256) {
                int layer = i >> 5, c = i & 31;
                const void* b1p = layer ? b1b : b1a;
                b1f_ws[i] = isbf ? bf2f(((const short*)b1p)[c])
                                 : ((const float*)b1p)[c];
            }
        }
        int t = bb * 256 + threadIdx.x;
        if (t < 2 * 32 * 1056) {
            int layer = t / (32 * 1056);
            int r = t - layer * (32 * 1056);
            int o = r / 1056, kp = r - o * 1056;
            const void* w2 = layer ? w2b : w2a;
            const void* b2 = layer ? b2b : b2a;
            int idx; const void* sp;
            if (kp < 1024) { int kk = kp >> 5, i = kp & 31; idx = kk * 1024 + i * 32 + o; sp = w2; }
            else           { int i = kp - 1024;             idx = i * 32 + o;             sp = b2; }
            short v = isbf ? ((const short*)sp)[idx] : (short)f2bf(((const float*)sp)[idx]);
            (layer ? W2Tb : W2Ta)[o * 1056 + kp] = v;
            return;
        }
        int u = t - 2 * 32 * 1056;
        if (u < NE * 2 && !isbf) {  // 400000 threads x 8 elems
            const float* p = (const float*)ea + (size_t)u * 8;
            f32x4 f0 = *(const f32x4*)p;
            f32x4 f1 = *(const f32x4*)(p + 4);
            union { unsigned int d[4]; short8 v; } o8;
            o8.d[0] = pack2bf(f0[0], f0[1]);
            o8.d[1] = pack2bf(f0[2], f0[3]);
            o8.d[2] = pack2bf(f1[0], f1[1]);
            o8.d[3] = pack2bf(f1[2], f1[3]);
            *(short8*)&ea_ws[(size_t)u * 8] = o8.v;
        }
        return;
    }
    {  // ---- role C: zero aggB ----
        int idx = (b - 4327) * 256 + threadIdx.x;
        if (idx < NN * 32 / 4) {
            f32x4 z = {0.f, 0.f, 0.f, 0.f};
            ((f32x4*)aggB)[idx] = z;
        }
    }
}

// ------------------------------------------------------------------ edge kernel:
// FULL-K, 64 edges per wave, W2T from L2 -- NOW with an explicit DEPTH-4
// software-pipelined load queue for the B-fragments.  r10's VGPR_Count=56
// proved the compiler kept <=1 W2T bf-pair in flight -> 66 SERIALIZED L2
// loads x ~300-800cy contended latency = the invariant ~60us floor.  The
// 4-entry register queue (statically indexed under full unroll) keeps 8
// loads in flight, covering L2 latency with the ~100cy/step compute.
// Bias step unified into the 33-step stream (W2T row = contiguous 33x32).
// Atomics stay once-per-output; no __syncthreads in the job path; h1
// per-wave LDS (broadcast reads, 0 conflicts).  LDS 17.4KB; VGPR ~110.
// layer2==1: block prologue atomically adds its slice of
// aggB = lrelu(aggA)@root2 + bias2 (aggB pre-zeroed); gathered rows get
// lrelu inline.
__global__ __launch_bounds__(256, 4) void k_edge(
    const float* __restrict__ h_in,   // [N,32] fp32 (h0 or aggA)
    const short* __restrict__ W2T,    // [32][1056] bf16 (read via L2)
    const short* __restrict__ w1pre,  // [32 c][16 q] bf16 transposed (this layer)
    const float* __restrict__ b1pre,  // [32] fp32 (this layer)
    const int* __restrict__ src, const int* __restrict__ dst,
    const short* __restrict__ ea_bf,  // [E][16] bf16 (pre-converted or orig)
    const short* __restrict__ ea_ws,
    const unsigned int* xdet,
    float* agg,
    const int layer2, const void* rootp, const void* biasp) {
    __shared__ __align__(16) short h1l[4 * 32 * 68];  // per-wave [kk32][edge64+pad]

    const int isbf = detect_isbf(xdet);
    const short* eap = isbf ? ea_bf : ea_ws;

    if (layer2) {  // ---- fused k_mid: this block's slice of aggB root-init ----
        const int base = blockIdx.x * L2SLICE;
        for (int i = threadIdx.x; i < L2SLICE; i += 256) {
            int t = base + i;
            if (t < NN * 32) {
                int v = t >> 5, c = t & 31;
                const float* ar = h_in + (size_t)v * 32;
                float acc = isbf ? bf2f(((const short*)biasp)[c]) : ((const float*)biasp)[c];
#pragma unroll
                for (int q = 0; q < 32; ++q) {
                    float hv = ar[q];
                    hv = hv > 0.f ? hv : 0.01f * hv;
                    float wv = isbf ? bf2f(((const short*)rootp)[q * 32 + c])
                                    : ((const float*)rootp)[q * 32 + c];
                    acc += hv * wv;
                }
                atomicAdd(&agg[t], acc);
            }
        }
    }

    const int lane = threadIdx.x & 63;
    const int wid  = threadIdx.x >> 6;
    const int m    = lane & 15;
    const int quad = lane >> 4;
    const int wb   = wid * (32 * 68);

    const int w = blockIdx.x * 4 + wid;  // one 64-edge job per wave
    if (w >= NWJOBS) return;

    // B-fragments of w1 for kk=m and kk=m+16 (K padded 16->32, quads 2,3 zero)
    short8 w1lo = {0, 0, 0, 0, 0, 0, 0, 0};
    short8 w1hi = {0, 0, 0, 0, 0, 0, 0, 0};
    if (quad < 2) {
        w1lo = *(const short8*)&w1pre[m * 16 + ((quad & 1) << 3)];
        w1hi = *(const short8*)&w1pre[(m + 16) * 16 + ((quad & 1) << 3)];
    }
    const float b1lo = b1pre[m];
    const float b1hi = b1pre[m + 16];
    const f32x4 zero4 = {0.f, 0.f, 0.f, 0.f};

    // ---- prologue: all loads for the 64 edges ----
    const int e0 = w << 6;
    short8 eafc[4];
    f32x4 hs[4][2];
    int4v dv[4];
    {
        int s0[4];
#pragma unroll
        for (int mt = 0; mt < 4; ++mt) {
            eafc[mt] = *(const short8*)&eap[(size_t)(e0 + mt * 16 + m) * 16 + ((quad & 1) << 3)];
            s0[mt] = src[e0 + mt * 16 + m];
            dv[mt] = *(const int4v*)&dst[e0 + mt * 16 + (quad << 2)];
        }
#pragma unroll
        for (int mt = 0; mt < 4; ++mt) {
            const float* hr = h_in + (size_t)s0[mt] * 32 + (quad << 3);
            hs[mt][0] = *(const f32x4*)hr;
            hs[mt][1] = *(const f32x4*)(hr + 4);
        }
    }

    // ---- phase 1: h1 = relu(ea@w1+b1), all 32 kk -> bf16 [kk][edge] LDS ----
#pragma unroll
    for (int mt = 0; mt < 4; ++mt) {
        f32x4 alo = __builtin_amdgcn_mfma_f32_16x16x32_bf16(eafc[mt], w1lo, zero4, 0, 0, 0);
        f32x4 ahi = __builtin_amdgcn_mfma_f32_16x16x32_bf16(eafc[mt], w1hi, zero4, 0, 0, 0);
        float v0 = fmaxf(alo[0] + b1lo, 0.f);
        float v1 = fmaxf(alo[1] + b1lo, 0.f);
        float v2 = fmaxf(alo[2] + b1lo, 0.f);
        float v3 = fmaxf(alo[3] + b1lo, 0.f);
        uint2v dlo; dlo[0] = pack2bf(v0, v1); dlo[1] = pack2bf(v2, v3);
        // C/D: row(edge-local)=quad*4+r, col(kk)=m -> h1l[kk][mt*16+quad*4+r]
        *(uint2v*)&h1l[wb + m * 68 + (mt << 4) + (quad << 2)] = dlo;
        v0 = fmaxf(ahi[0] + b1hi, 0.f);
        v1 = fmaxf(ahi[1] + b1hi, 0.f);
        v2 = fmaxf(ahi[2] + b1hi, 0.f);
        v3 = fmaxf(ahi[3] + b1hi, 0.f);
        uint2v dhi; dhi[0] = pack2bf(v0, v1); dhi[1] = pack2bf(v2, v3);
        *(uint2v*)&h1l[wb + (m + 16) * 68 + (mt << 4) + (quad << 2)] = dhi;
    }
    __asm volatile("s_waitcnt lgkmcnt(0)" ::: "memory");

    // ---- convert hsrc -> bf16 A-fragment (lrelu inline for layer 2) ----
    short8 hsbf[4];
#pragma unroll
    for (int mt = 0; mt < 4; ++mt) {
        f32x4 g0 = hs[mt][0], g1 = hs[mt][1];
        if (layer2) {
#pragma unroll
            for (int p = 0; p < 4; ++p) {
                g0[p] = g0[p] > 0.f ? g0[p] : 0.01f * g0[p];
                g1[p] = g1[p] > 0.f ? g1[p] : 0.01f * g1[p];
            }
        }
        union { unsigned int du[4]; short8 v; } a;
        a.du[0] = pack2bf(g0[0], g0[1]);
        a.du[1] = pack2bf(g0[2], g0[3]);
        a.du[2] = pack2bf(g1[0], g1[1]);
        a.du[3] = pack2bf(g1[2], g1[3]);
        hsbf[mt] = a.v;
    }

    // ---- phase 2: 33 uniform K-steps (s=32 is the bias block), B-fragments
    // streamed through a DEPTH-4 register queue so 8 L2 loads stay in flight ----
    const short* wr0 = W2T + m * 1056 + (quad << 3);
    const short* wr1 = W2T + (m + 16) * 1056 + (quad << 3);
    f32x4 acc0[4] = {zero4, zero4, zero4, zero4};
    f32x4 acc1[4] = {zero4, zero4, zero4, zero4};
    short8 q0[4], q1[4];
#pragma unroll
    for (int p = 0; p < 4; ++p) {
        q0[p] = *(const short8*)(wr0 + (p << 5));
        q1[p] = *(const short8*)(wr1 + (p << 5));
    }
#pragma unroll
    for (int s = 0; s < 33; ++s) {
        short8 bf0 = q0[s & 3];
        short8 bf1 = q1[s & 3];
        if (s + 4 < 33) {  // refill queue 4 steps ahead (static index: full unroll)
            q0[s & 3] = *(const short8*)(wr0 + ((s + 4) << 5));
            q1[s & 3] = *(const short8*)(wr1 + ((s + 4) << 5));
        }
        if (s < 32) {
#pragma unroll
            for (int mt = 0; mt < 4; ++mt) {
                uint2v hd = *(const uint2v*)&h1l[wb + s * 68 + (mt << 4) + (quad << 2)];
                f32x4 hv;
                hv[0] = __builtin_bit_cast(float, hd[0] << 16);
                hv[1] = __builtin_bit_cast(float, hd[0] & 0xffff0000u);
                hv[2] = __builtin_bit_cast(float, hd[1] << 16);
                hv[3] = __builtin_bit_cast(float, hd[1] & 0xffff0000u);
                f32x4 u0 = __builtin_amdgcn_mfma_f32_16x16x32_bf16(hsbf[mt], bf0, zero4, 0, 0, 0);
                f32x4 u1 = __builtin_amdgcn_mfma_f32_16x16x32_bf16(hsbf[mt], bf1, zero4, 0, 0, 0);
                acc0[mt] += hv * u0;
                acc1[mt] += hv * u1;
            }
        } else {  // bias block (coefficient 1.0): MFMA direct into acc
#pragma unroll
            for (int mt = 0; mt < 4; ++mt) {
                acc0[mt] = __builtin_amdgcn_mfma_f32_16x16x32_bf16(hsbf[mt], bf0, acc0[mt], 0, 0, 0);
                acc1[mt] = __builtin_amdgcn_mfma_f32_16x16x32_bf16(hsbf[mt], bf1, acc1[mt], 0, 0, 0);
            }
        }
    }

    // ---- epilogue: atomic scatter (32 per edge row -- ONCE per pair) ----
#pragma unroll
    for (int mt = 0; mt < 4; ++mt) {
#pragma unroll
        for (int r = 0; r < 4; ++r) {
            float* ap = agg + (size_t)dv[mt][r] * 32 + m;
            atomicAdd(ap, acc0[mt][r]);
            atomicAdd(ap + 16, acc1[mt][r]);
        }
    }
}

// ------------------------------------------------------------------ merged tail:
// ONE block per graph (batch is sorted -> binary-search the node range).
// Does lrelu+atom_embs write, pooled sum (block-local, NO atomics), L2
// normalize, and the fc head -- replaces k_final_nodes + k_graph_out and
// the pooled workspace.  No cross-block sync anywhere.
__global__ __launch_bounds__(256) void k_final(
    const float* __restrict__ agg, const int* __restrict__ batch,
    const unsigned int* xdet, void* __restrict__ out,
    const void* fcw, const void* fcb) {
    const int isbf = detect_isbf(xdet);
    const int g = blockIdx.x;
    __shared__ int srange[2];
    __shared__ float gacc[8][32];
    __shared__ float pn[32];
    if (threadIdx.x < 2) {  // lower_bound(batch, g) and lower_bound(batch, g+1)
        int target = g + (int)threadIdx.x;
        int lo = 0, hi = NN;
        while (lo < hi) {
            int mid = (lo + hi) >> 1;
            if (batch[mid] < target) lo = mid + 1; else hi = mid;
        }
        srange[threadIdx.x] = lo;
    }
    __syncthreads();
    const int ns = srange[0], ne = srange[1];
    const int c = threadIdx.x & 31;
    float psum = 0.f;
    for (int idx = ns * 32 + threadIdx.x; idx < ne * 32; idx += 256) {
        float v = agg[idx];
        v = v > 0.f ? v : 0.01f * v;
        if (isbf) ((short*)out)[4096 + idx] = (short)f2bf(v);
        else      ((float*)out)[4096 + idx] = v;
        psum += v;   // stride 256 == 0 mod 32 -> this thread's column is fixed
    }
    gacc[threadIdx.x >> 5][c] = psum;
    __syncthreads();
    if (threadIdx.x < 32) {
        float p = 0.f;
#pragma unroll
        for (int r = 0; r < 8; ++r) p += gacc[r][threadIdx.x];
        float sq = p * p;
#pragma unroll
        for (int o = 16; o > 0; o >>= 1) sq += __shfl_xor(sq, o, 64);  // partners stay in [0,32)
        float inv = 1.0f / fmaxf(sqrtf(sq), 1e-12f);
        pn[threadIdx.x] = p * inv;
    }
    __syncthreads();
    if (threadIdx.x < 32) {
        const int t = threadIdx.x;
        float acc = isbf ? bf2f(((const short*)fcb)[t]) : ((const float*)fcb)[t];
#pragma unroll
        for (int q = 0; q < 32; ++q) {
            float wv = isbf ? bf2f(((const short*)fcw)[q * 32 + t])
                            : ((const float*)fcw)[q * 32 + t];
            acc += pn[q] * wv;
        }
        if (isbf) ((short*)out)[g * 32 + t] = (short)f2bf(acc);
        else      ((float*)out)[g * 32 + t] = acc;
    }
}

extern "C" void kernel_launch(void* const* d_in, const int* in_sizes, int n_in,
                              void* d_out, int out_size, void* d_ws, size_t ws_size,
                              hipStream_t stream) {
    (void)in_sizes; (void)n_in; (void)out_size; (void)ws_size;
    const void* x     = d_in[0];
    const int*  eidx  = (const int*)d_in[1];
    const void* ea    = d_in[2];
    const int*  batch = (const int*)d_in[3];
    const void* nfcw  = d_in[5];
    const void* nfcb  = d_in[6];
    const void* e1w1  = d_in[7];
    const void* e1b1  = d_in[8];
    const void* e1w2  = d_in[9];
    const void* e1b2  = d_in[10];
    const void* root1 = d_in[11];
    const void* bias1 = d_in[12];
    const void* e2w1  = d_in[13];
    const void* e2b1  = d_in[14];
    const void* e2w2  = d_in[15];
    const void* e2b2  = d_in[16];
    const void* root2 = d_in[17];
    const void* bias2 = d_in[18];
    const void* fcw   = d_in[19];
    const void* fcb   = d_in[20];
    const unsigned int* xdet = (const unsigned int*)x;

    char* ws = (char*)d_ws;
    float* h0     = (float*)ws; ws += (size_t)NN * 32 * 4;
    float* aggA   = (float*)ws; ws += (size_t)NN * 32 * 4;
    float* aggB   = (float*)ws; ws += (size_t)NN * 32 * 4;
    short* W2T1   = (short*)ws; ws += 32 * 1056 * 2;
    short* W2T2   = (short*)ws; ws += 32 * 1056 * 2;
    short* w1t_ws = (short*)ws; ws += 1024 * 2;
    float* b1f_ws = (float*)ws; ws += 64 * 4;
    short* ea_ws  = (short*)ws; ws += (size_t)NE * 16 * 2;

    const int* srcp = eidx;
    const int* dstp = eidx + NE;

    // kernel 1: embed(2500) + prep(1827) + aggB-zero(625) = 4952 blocks
    k_prep_all<<<4952, 256, 0, stream>>>(
        x, nfcw, nfcb, root1, bias1,
        e1w2, e1b2, e2w2, e2b2, e1w1, e1b1, e2w1, e2b1, ea,
        h0, aggA, aggB, W2T1, W2T2, w1t_ws, b1f_ws, ea_ws);

    // layer 1 (full-K, 64 edges per wave, pipelined W2T stream)
    k_edge<<<EGRID, 256, 0, stream>>>(h0, W2T1, w1t_ws, b1f_ws, srcp, dstp,
                                      (const short*)ea, ea_ws, xdet, aggA,
                                      0, nullptr, nullptr);
    // layer 2 (fused root2-init + inline lrelu on gathered aggA)
    k_edge<<<EGRID, 256, 0, stream>>>(aggA, W2T2, w1t_ws + 512, b1f_ws + 32, srcp, dstp,
                                      (const short*)ea, ea_ws, xdet, aggB,
                                      1, root2, bias2);
    // merged tail: node output + per-graph pool + normalize + fc head
    k_final<<<NG, 256, 0, stream>>>(aggB, batch, xdet, d_out, fcw, fcb);
}

// Round 12
// 196.182 us; speedup vs baseline: 2.0661x; 1.1139x over previous
//
#include <hip/hip_runtime.h>
#include <stdint.h>

#define NN 20000
#define NE 200000
#define NG 128
#define NWJOBS 3125  // 64-edge full-K jobs, one per wave
#define EBLK 256     // k_edge blocks: one per CU, 16 waves each

typedef __attribute__((ext_vector_type(8))) short short8;
typedef __attribute__((ext_vector_type(4))) float f32x4;
typedef __attribute__((ext_vector_type(4))) int   int4v;
typedef __attribute__((ext_vector_type(2))) unsigned int uint2v;

static __device__ __forceinline__ float bf2f(short s) {
    union { unsigned int u; float f; } x;
    x.u = ((unsigned int)(unsigned short)s) << 16;
    return x.f;
}
static __device__ __forceinline__ unsigned short f2bf(float f) {
    unsigned int u = __builtin_bit_cast(unsigned int, f);
    u += 0x7fffu + ((u >> 16) & 1u);
    return (unsigned short)(u >> 16);
}
// pack two floats into a dword of two bf16 (a low, b high): 2 add + 1 v_perm
static __device__ __forceinline__ unsigned int pack2bf(float a, float b) {
    unsigned int u0 = __builtin_bit_cast(unsigned int, a) + 0x8000u;
    unsigned int u1 = __builtin_bit_cast(unsigned int, b) + 0x8000u;
    return __builtin_amdgcn_perm(u1, u0, 0x07060302u);
}
// per-wave inline dtype detect: all lanes read x[0..63]; bf16 low-short exp
// field lands in [100,140] w.p. ~0.99 vs ~0.16 for fp32 mantissa bits.
static __device__ __forceinline__ int detect_isbf(const unsigned int* x) {
    unsigned int u = x[threadIdx.x & 63];
    unsigned int el = (u >> 7) & 0xffu;
    unsigned long long bm = __ballot((el >= 100u) && (el <= 140u));
    return __popcll(bm) > 32;
}

// ------------------------------------------------------------------ kernel 1:
// block-role split (all roles independent; all must precede edge1):
//   blocks [0,2500):    node embed + layer-1 root init (h0, aggA)
//   blocks [2500,4327): W2T transpose, w1t/b1f, ea -> bf16 workspace
//   blocks [4327,4952): zero aggB (for edge2's atomic-init of the root term)
__global__ __launch_bounds__(256) void k_prep_all(
    const void* x, const void* nfcw, const void* nfcb,
    const void* root1, const void* bias1,
    const void* w2a, const void* b2a, const void* w2b, const void* b2b,
    const void* w1a, const void* b1a, const void* w1b, const void* b1b,
    const void* ea,
    float* __restrict__ h0, float* __restrict__ aggA, float* __restrict__ aggB,
    short* __restrict__ W2Ta, short* __restrict__ W2Tb,
    short* __restrict__ w1t_ws, float* __restrict__ b1f_ws,
    short* __restrict__ ea_ws) {
    const int isbf = detect_isbf((const unsigned int*)x);
    const int b = blockIdx.x;

    if (b < 2500) {  // ---- role A: embed + aggA init (vectorized x loads) ----
        __shared__ float wf[64 * 32];
        __shared__ float rf[32 * 32];
        __shared__ float bfs[32];
        __shared__ float rb[32];
        __shared__ float xrow[8][66];   // staged x rows, fp32
        __shared__ float hrow[8][33];
        for (int i = threadIdx.x; i < 64 * 32; i += 256)
            wf[i] = isbf ? bf2f(((const short*)nfcw)[i]) : ((const float*)nfcw)[i];
        for (int i = threadIdx.x; i < 32 * 32; i += 256)
            rf[i] = isbf ? bf2f(((const short*)root1)[i]) : ((const float*)root1)[i];
        if (threadIdx.x < 32) {
            bfs[threadIdx.x] = isbf ? bf2f(((const short*)nfcb)[threadIdx.x])
                                    : ((const float*)nfcb)[threadIdx.x];
            rb[threadIdx.x]  = isbf ? bf2f(((const short*)bias1)[threadIdx.x])
                                    : ((const float*)bias1)[threadIdx.x];
        }
        int t = b * 256 + threadIdx.x;
        int v = t >> 5, c = t & 31, vl = threadIdx.x >> 5;
        // coalesced row staging: 32 threads load the row's 64 values
        if (isbf) {
            const short* xr = (const short*)x + (size_t)v * 64;
            xrow[vl][c]      = bf2f(xr[c]);
            xrow[vl][32 + c] = bf2f(xr[32 + c]);
        } else {
            const float* xr = (const float*)x + (size_t)v * 64;
            xrow[vl][c]      = xr[c];
            xrow[vl][32 + c] = xr[32 + c];
        }
        __syncthreads();
        float acc = bfs[c];
#pragma unroll
        for (int q = 0; q < 64; ++q) acc += xrow[vl][q] * wf[q * 32 + c];
        float hv = acc > 0.f ? acc : 0.01f * acc;
        h0[t] = hv;
        hrow[vl][c] = hv;
        __syncthreads();
        float a2 = rb[c];
#pragma unroll
        for (int q = 0; q < 32; ++q) a2 += hrow[vl][q] * rf[q * 32 + c];
        aggA[t] = a2;
        return;
    }
    if (b < 4327) {  // ---- role B: weight prep ----
        const int bb = b - 2500;
        if (bb == 1) {
            for (int i = threadIdx.x; i < 1024; i += 256) {
                int layer = i >> 9, jj = i & 511, c = jj >> 4, q = jj & 15;
                const void* w1p = layer ? w1b : w1a;
                w1t_ws[i] = isbf ? ((const short*)w1p)[q * 32 + c]
                                 : (short)f2bf(((const float*)w1p)[q * 32 + c]);
            }
            for (int i = threadIdx.x; i < 64; i += 256) {
                int layer = i >> 5, c = i & 31;
                const void* b1p = layer ? b1b : b1a;
                b1f_ws[i] = isbf ? bf2f(((const short*)b1p)[c])
                                 : ((const float*)b1p)[c];
            }
        }
        int t = bb * 256 + threadIdx.x;
        if (t < 2 * 32 * 1056) {
            int layer = t / (32 * 1056);
            int r = t - layer * (32 * 1056);
            int o = r / 1056, kp = r - o * 1056;
            const void* w2 = layer ? w2b : w2a;
            const void* b2 = layer ? b2b : b2a;
            int idx; const void* sp;
            if (kp < 1024) { int kk = kp >> 5, i = kp & 31; idx = kk * 1024 + i * 32 + o; sp = w2; }
            else           { int i = kp - 1024;             idx = i * 32 + o;             sp = b2; }
            short v = isbf ? ((const short*)sp)[idx] : (short)f2bf(((const float*)sp)[idx]);
            (layer ? W2Tb : W2Ta)[o * 1056 + kp] = v;
            return;
        }
        int u = t - 2 * 32 * 1056;
        if (u < NE * 2 && !isbf) {  // 400000 threads x 8 elems
            const float* p = (const float*)ea + (size_t)u * 8;
            f32x4 f0 = *(const f32x4*)p;
            f32x4 f1 = *(const f32x4*)(p + 4);
            union { unsigned int d[4]; short8 v; } o8;
            o8.d[0] = pack2bf(f0[0], f0[1]);
            o8.d[1] = pack2bf(f0[2], f0[3]);
            o8.d[2] = pack2bf(f1[0], f1[1]);
            o8.d[3] = pack2bf(f1[2], f1[3]);
            *(short8*)&ea_ws[(size_t)u * 8] = o8.v;
        }
        return;
    }
    {  // ---- role C: zero aggB ----
        int idx = (b - 4327) * 256 + threadIdx.x;
        if (idx < NN * 32 / 4) {
            f32x4 z = {0.f, 0.f, 0.f, 0.f};
            ((f32x4*)aggB)[idx] = z;
        }
    }
}

// ------------------------------------------------------------------ edge kernel:
// ONE 1024-thread block (16 waves) PER CU; W2T staged in LDS ONCE PER CU.
// r11's counters showed all waves co-resident, 1 job each, 54us = single-job
// latency with no pipe >20% busy -> the shared binder is the per-CU VMEM
// request queue (each W2T load = 16 scattered 64B lines; 17k line-reqs/CU
// just for W2T redundant re-reads).  This version: W2T fetched once per CU
// (1056 lines), B-fragments via ds_read_b128 from padded LDS (row stride
// 1058 shorts = odd dword stride -> 2-way banks, free), h1 per-wave LDS.
// Full-K retained -> atomics stay once-per-output (6.4M).  One __syncthreads
// total.  LDS 137.3KB -> 1 block/CU, 16 waves.  Job = wid*256+blockIdx so
// all 256 CUs carry 12-13 active waves.
// layer2==1: block prologue atomically adds its 2500-elem slice of
// aggB = lrelu(aggA)@root2 + bias2 (aggB pre-zeroed); gathered rows get
// lrelu inline.
__global__ __launch_bounds__(1024, 4) void k_edge(
    const float* __restrict__ h_in,   // [N,32] fp32 (h0 or aggA)
    const short* __restrict__ W2T,    // [32][1056] bf16
    const short* __restrict__ w1pre,  // [32 c][16 q] bf16 transposed (this layer)
    const float* __restrict__ b1pre,  // [32] fp32 (this layer)
    const int* __restrict__ src, const int* __restrict__ dst,
    const short* __restrict__ ea_bf,  // [E][16] bf16 (pre-converted or orig)
    const short* __restrict__ ea_ws,
    const unsigned int* xdet,
    float* agg,
    const int layer2, const void* rootp, const void* biasp) {
    __shared__ __align__(16) short w2t[32 * 1058];    // 67.7KB, odd dword stride
    __shared__ __align__(16) short h1l[16 * 32 * 68]; // 69.6KB, per-wave [kk32][edge64+pad]

    const int isbf = detect_isbf(xdet);
    const short* eap = isbf ? ea_bf : ea_ws;

    // ---- cooperative W2T stage: 67.7KB once per CU ----
    for (int c = threadIdx.x; c < 32 * 132; c += 1024) {
        int o = c / 132, t8 = c - o * 132;
        *(short8*)&w2t[o * 1058 + (t8 << 3)] = *(const short8*)&W2T[o * 1056 + (t8 << 3)];
    }
    if (layer2) {  // ---- fused k_mid: this block's 2500-elem slice of aggB init ----
        const int base = blockIdx.x * 2500;
        for (int i = threadIdx.x; i < 2500; i += 1024) {
            int t = base + i;
            int v = t >> 5, c = t & 31;
            const float* ar = h_in + (size_t)v * 32;
            float acc = isbf ? bf2f(((const short*)biasp)[c]) : ((const float*)biasp)[c];
#pragma unroll
            for (int q = 0; q < 32; ++q) {
                float hv = ar[q];
                hv = hv > 0.f ? hv : 0.01f * hv;
                float wv = isbf ? bf2f(((const short*)rootp)[q * 32 + c])
                                : ((const float*)rootp)[q * 32 + c];
                acc += hv * wv;
            }
            atomicAdd(&agg[t], acc);
        }
    }
    __syncthreads();   // the only barrier: w2t ready for all waves

    const int lane = threadIdx.x & 63;
    const int wid  = threadIdx.x >> 6;   // 0..15
    const int m    = lane & 15;
    const int quad = lane >> 4;
    const int wb   = wid * (32 * 68);

    // job layout keeps every block (=CU) carrying 12-13 active waves
    const int w = wid * EBLK + (int)blockIdx.x;
    if (w >= NWJOBS) return;

    // B-fragments of w1 for kk=m and kk=m+16 (K padded 16->32, quads 2,3 zero)
    short8 w1lo = {0, 0, 0, 0, 0, 0, 0, 0};
    short8 w1hi = {0, 0, 0, 0, 0, 0, 0, 0};
    if (quad < 2) {
        w1lo = *(const short8*)&w1pre[m * 16 + ((quad & 1) << 3)];
        w1hi = *(const short8*)&w1pre[(m + 16) * 16 + ((quad & 1) << 3)];
    }
    const float b1lo = b1pre[m];
    const float b1hi = b1pre[m + 16];
    const f32x4 zero4 = {0.f, 0.f, 0.f, 0.f};

    // ---- prologue: all loads for the 64 edges ----
    const int e0 = w << 6;
    short8 eafc[4];
    f32x4 hs[4][2];
    int4v dv[4];
    {
        int s0[4];
#pragma unroll
        for (int mt = 0; mt < 4; ++mt) {
            eafc[mt] = *(const short8*)&eap[(size_t)(e0 + mt * 16 + m) * 16 + ((quad & 1) << 3)];
            s0[mt] = src[e0 + mt * 16 + m];
            dv[mt] = *(const int4v*)&dst[e0 + mt * 16 + (quad << 2)];
        }
#pragma unroll
        for (int mt = 0; mt < 4; ++mt) {
            const float* hr = h_in + (size_t)s0[mt] * 32 + (quad << 3);
            hs[mt][0] = *(const f32x4*)hr;
            hs[mt][1] = *(const f32x4*)(hr + 4);
        }
    }

    // ---- phase 1: h1 = relu(ea@w1+b1), all 32 kk -> bf16 [kk][edge] LDS ----
#pragma unroll
    for (int mt = 0; mt < 4; ++mt) {
        f32x4 alo = __builtin_amdgcn_mfma_f32_16x16x32_bf16(eafc[mt], w1lo, zero4, 0, 0, 0);
        f32x4 ahi = __builtin_amdgcn_mfma_f32_16x16x32_bf16(eafc[mt], w1hi, zero4, 0, 0, 0);
        float v0 = fmaxf(alo[0] + b1lo, 0.f);
        float v1 = fmaxf(alo[1] + b1lo, 0.f);
        float v2 = fmaxf(alo[2] + b1lo, 0.f);
        float v3 = fmaxf(alo[3] + b1lo, 0.f);
        uint2v dlo; dlo[0] = pack2bf(v0, v1); dlo[1] = pack2bf(v2, v3);
        // C/D: row(edge-local)=quad*4+r, col(kk)=m -> h1l[kk][mt*16+quad*4+r]
        *(uint2v*)&h1l[wb + m * 68 + (mt << 4) + (quad << 2)] = dlo;
        v0 = fmaxf(ahi[0] + b1hi, 0.f);
        v1 = fmaxf(ahi[1] + b1hi, 0.f);
        v2 = fmaxf(ahi[2] + b1hi, 0.f);
        v3 = fmaxf(ahi[3] + b1hi, 0.f);
        uint2v dhi; dhi[0] = pack2bf(v0, v1); dhi[1] = pack2bf(v2, v3);
        *(uint2v*)&h1l[wb + (m + 16) * 68 + (mt << 4) + (quad << 2)] = dhi;
    }
    __asm volatile("s_waitcnt lgkmcnt(0)" ::: "memory");  // own-wave h1 writes only

    // ---- convert hsrc -> bf16 A-fragment (lrelu inline for layer 2) ----
    short8 hsbf[4];
#pragma unroll
    for (int mt = 0; mt < 4; ++mt) {
        f32x4 g0 = hs[mt][0], g1 = hs[mt][1];
        if (layer2) {
#pragma unroll
            for (int p = 0; p < 4; ++p) {
                g0[p] = g0[p] > 0.f ? g0[p] : 0.01f * g0[p];
                g1[p] = g1[p] > 0.f ? g1[p] : 0.01f * g1[p];
            }
        }
        union { unsigned int du[4]; short8 v; } a;
        a.du[0] = pack2bf(g0[0], g0[1]);
        a.du[1] = pack2bf(g0[2], g0[3]);
        a.du[2] = pack2bf(g1[0], g1[1]);
        a.du[3] = pack2bf(g1[2], g1[3]);
        hsbf[mt] = a.v;
    }

    // ---- phase 2: 33 uniform K-steps, B-fragments from LDS (ds_read_b128) ----
    f32x4 acc0[4] = {zero4, zero4, zero4, zero4};
    f32x4 acc1[4] = {zero4, zero4, zero4, zero4};
#pragma unroll
    for (int s = 0; s < 33; ++s) {
        short8 bf0 = *(const short8*)&w2t[m * 1058 + (s << 5) + (quad << 3)];
        short8 bf1 = *(const short8*)&w2t[(m + 16) * 1058 + (s << 5) + (quad << 3)];
        if (s < 32) {
#pragma unroll
            for (int mt = 0; mt < 4; ++mt) {
                uint2v hd = *(const uint2v*)&h1l[wb + s * 68 + (mt << 4) + (quad << 2)];
                f32x4 hv;
                hv[0] = __builtin_bit_cast(float, hd[0] << 16);
                hv[1] = __builtin_bit_cast(float, hd[0] & 0xffff0000u);
                hv[2] = __builtin_bit_cast(float, hd[1] << 16);
                hv[3] = __builtin_bit_cast(float, hd[1] & 0xffff0000u);
                f32x4 u0 = __builtin_amdgcn_mfma_f32_16x16x32_bf16(hsbf[mt], bf0, zero4, 0, 0, 0);
                f32x4 u1 = __builtin_amdgcn_mfma_f32_16x16x32_bf16(hsbf[mt], bf1, zero4, 0, 0, 0);
                acc0[mt] += hv * u0;
                acc1[mt] += hv * u1;
            }
        } else {  // bias block (coefficient 1.0): MFMA direct into acc
#pragma unroll
            for (int mt = 0; mt < 4; ++mt) {
                acc0[mt] = __builtin_amdgcn_mfma_f32_16x16x32_bf16(hsbf[mt], bf0, acc0[mt], 0, 0, 0);
                acc1[mt] = __builtin_amdgcn_mfma_f32_16x16x32_bf16(hsbf[mt], bf1, acc1[mt], 0, 0, 0);
            }
        }
    }

    // ---- epilogue: atomic scatter (32 per edge row -- ONCE per pair) ----
#pragma unroll
    for (int mt = 0; mt < 4; ++mt) {
#pragma unroll
        for (int r = 0; r < 4; ++r) {
            float* ap = agg + (size_t)dv[mt][r] * 32 + m;
            atomicAdd(ap, acc0[mt][r]);
            atomicAdd(ap + 16, acc1[mt][r]);
        }
    }
}

// ------------------------------------------------------------------ merged tail:
// ONE block per graph (batch is sorted -> binary-search the node range).
// Does lrelu+atom_embs write, pooled sum (block-local, NO atomics), L2
// normalize, and the fc head.  No cross-block sync anywhere.
__global__ __launch_bounds__(256) void k_final(
    const float* __restrict__ agg, const int* __restrict__ batch,
    const unsigned int* xdet, void* __restrict__ out,
    const void* fcw, const void* fcb) {
    const int isbf = detect_isbf(xdet);
    const int g = blockIdx.x;
    __shared__ int srange[2];
    __shared__ float gacc[8][32];
    __shared__ float pn[32];
    if (threadIdx.x < 2) {  // lower_bound(batch, g) and lower_bound(batch, g+1)
        int target = g + (int)threadIdx.x;
        int lo = 0, hi = NN;
        while (lo < hi) {
            int mid = (lo + hi) >> 1;
            if (batch[mid] < target) lo = mid + 1; else hi = mid;
        }
        srange[threadIdx.x] = lo;
    }
    __syncthreads();
    const int ns = srange[0], ne = srange[1];
    const int c = threadIdx.x & 31;
    float psum = 0.f;
    for (int idx = ns * 32 + threadIdx.x; idx < ne * 32; idx += 256) {
        float v = agg[idx];
        v = v > 0.f ? v : 0.01f * v;
        if (isbf) ((short*)out)[4096 + idx] = (short)f2bf(v);
        else      ((float*)out)[4096 + idx] = v;
        psum += v;   // stride 256 == 0 mod 32 -> this thread's column is fixed
    }
    gacc[threadIdx.x >> 5][c] = psum;
    __syncthreads();
    if (threadIdx.x < 32) {
        float p = 0.f;
#pragma unroll
        for (int r = 0; r < 8; ++r) p += gacc[r][threadIdx.x];
        float sq = p * p;
#pragma unroll
        for (int o = 16; o > 0; o >>= 1) sq += __shfl_xor(sq, o, 64);  // partners stay in [0,32)
        float inv = 1.0f / fmaxf(sqrtf(sq), 1e-12f);
        pn[threadIdx.x] = p * inv;
    }
    __syncthreads();
    if (threadIdx.x < 32) {
        const int t = threadIdx.x;
        float acc = isbf ? bf2f(((const short*)fcb)[t]) : ((const float*)fcb)[t];
#pragma unroll
        for (int q = 0; q < 32; ++q) {
            float wv = isbf ? bf2f(((const short*)fcw)[q * 32 + t])
                            : ((const float*)fcw)[q * 32 + t];
            acc += pn[q] * wv;
        }
        if (isbf) ((short*)out)[g * 32 + t] = (short)f2bf(acc);
        else      ((float*)out)[g * 32 + t] = acc;
    }
}

extern "C" void kernel_launch(void* const* d_in, const int* in_sizes, int n_in,
                              void* d_out, int out_size, void* d_ws, size_t ws_size,
                              hipStream_t stream) {
    (void)in_sizes; (void)n_in; (void)out_size; (void)ws_size;
    const void* x     = d_in[0];
    const int*  eidx  = (const int*)d_in[1];
    const void* ea    = d_in[2];
    const int*  batch = (const int*)d_in[3];
    const void* nfcw  = d_in[5];
    const void* nfcb  = d_in[6];
    const void* e1w1  = d_in[7];
    const void* e1b1  = d_in[8];
    const void* e1w2  = d_in[9];
    const void* e1b2  = d_in[10];
    const void* root1 = d_in[11];
    const void* bias1 = d_in[12];
    const void* e2w1  = d_in[13];
    const void* e2b1  = d_in[14];
    const void* e2w2  = d_in[15];
    const void* e2b2  = d_in[16];
    const void* root2 = d_in[17];
    const void* bias2 = d_in[18];
    const void* fcw   = d_in[19];
    const void* fcb   = d_in[20];
    const unsigned int* xdet = (const unsigned int*)x;

    char* ws = (char*)d_ws;
    float* h0     = (float*)ws; ws += (size_t)NN * 32 * 4;
    float* aggA   = (float*)ws; ws += (size_t)NN * 32 * 4;
    float* aggB   = (float*)ws; ws += (size_t)NN * 32 * 4;
    short* W2T1   = (short*)ws; ws += 32 * 1056 * 2;
    short* W2T2   = (short*)ws; ws += 32 * 1056 * 2;
    short* w1t_ws = (short*)ws; ws += 1024 * 2;
    float* b1f_ws = (float*)ws; ws += 64 * 4;
    short* ea_ws  = (short*)ws; ws += (size_t)NE * 16 * 2;

    const int* srcp = eidx;
    const int* dstp = eidx + NE;

    // kernel 1: embed(2500) + prep(1827) + aggB-zero(625) = 4952 blocks
    k_prep_all<<<4952, 256, 0, stream>>>(
        x, nfcw, nfcb, root1, bias1,
        e1w2, e1b2, e2w2, e2b2, e1w1, e1b1, e2w1, e2b1, ea,
        h0, aggA, aggB, W2T1, W2T2, w1t_ws, b1f_ws, ea_ws);

    // layer 1 (full-K, LDS-resident W2T, 16 waves/CU, 1 job/wave)
    k_edge<<<EBLK, 1024, 0, stream>>>(h0, W2T1, w1t_ws, b1f_ws, srcp, dstp,
                                      (const short*)ea, ea_ws, xdet, aggA,
                                      0, nullptr, nullptr);
    // layer 2 (fused root2-init + inline lrelu on gathered aggA)
    k_edge<<<EBLK, 1024, 0, stream>>>(aggA, W2T2, w1t_ws + 512, b1f_ws + 32, srcp, dstp,
                                      (const short*)ea, ea_ws, xdet, aggB,
                                      1, root2, bias2);
    // merged tail: node output + per-graph pool + normalize + fc head
    k_final<<<NG, 256, 0, stream>>>(aggB, batch, xdet, d_out, fcw, fcb);
}